// Round 12
// baseline (542.525 us; speedup 1.0000x reference)
//
#include <hip/hip_runtime.h>
#include <hip/hip_bf16.h>
#include <math.h>

#define NN 50000
#define EE 200000

typedef __bf16 bf16x8 __attribute__((ext_vector_type(8)));
typedef __bf16 bf16x4 __attribute__((ext_vector_type(4)));
typedef __bf16 bf16x2 __attribute__((ext_vector_type(2)));
typedef float f32x4 __attribute__((ext_vector_type(4)));

static __device__ __forceinline__ bf16x8 ld8(const __bf16* p) {
  return *reinterpret_cast<const bf16x8*>(p);
}
static __device__ __forceinline__ bf16x4 ld4(const __bf16* p) {
  return *reinterpret_cast<const bf16x4*>(p);
}
static __device__ __forceinline__ bf16x8 cvt8(const float* p) {
  const f32x4* q = reinterpret_cast<const f32x4*>(p);
  f32x4 a = q[0], b = q[1];
  bf16x8 r;
  r[0] = (__bf16)a[0]; r[1] = (__bf16)a[1]; r[2] = (__bf16)a[2]; r[3] = (__bf16)a[3];
  r[4] = (__bf16)b[0]; r[5] = (__bf16)b[1]; r[6] = (__bf16)b[2]; r[7] = (__bf16)b[3];
  return r;
}
static __device__ __forceinline__ bf16x8 zero8() {
  bf16x8 z;
  #pragma unroll
  for (int j = 0; j < 8; ++j) z[j] = (__bf16)0.0f;
  return z;
}

// ---------------- fused prep: cvta | wt | auxef | cq2 | auxte(l0) | hist | h0 ----------------
// block ranges: [0,2208) cvta, [2208,2400) wt, [2400,14900) auxef,
// [14900,14902) cq2, [14902,27402) auxte l0, [27402,28184) hist, [28184,28966) h0

__global__ __launch_bounds__(256) void k_prep(const float* __restrict__ inw,
                                              const float* __restrict__ wq,
                                              const float* __restrict__ wk,
                                              const float* __restrict__ wvw,
                                              const float* __restrict__ ow,
                                              const float* __restrict__ ef,
                                              const float* __restrict__ tim,
                                              const float* __restrict__ tew,
                                              const float* __restrict__ teph,
                                              const float* __restrict__ wqb,
                                              const int* __restrict__ ei,
                                              const float* __restrict__ nf,
                                              const float* __restrict__ mem,
                                              const float* __restrict__ inb,
                                              __bf16* __restrict__ cinw,
                                              __bf16* __restrict__ cwq,
                                              __bf16* __restrict__ cwk,
                                              __bf16* __restrict__ cwv,
                                              __bf16* __restrict__ cow,
                                              __bf16* __restrict__ twk,
                                              __bf16* __restrict__ aux,
                                              float* __restrict__ cq,
                                              int* __restrict__ cnt,
                                              __bf16* __restrict__ hb) {
  __shared__ __bf16 As[64][264];
  const int b = blockIdx.x;
  if (b < 2208) {
    int i = b * 256 + threadIdx.x;
    if (i < 65536) cinw[i] = (__bf16)inw[i];
    else if (i < 204800) { int j = i - 65536;  cwq[j] = (__bf16)wq[j]; }
    else if (i < 376832) { int j = i - 204800; cwk[j] = (__bf16)wk[j]; }
    else if (i < 548864) { int j = i - 376832; cwv[j] = (__bf16)wvw[j]; }
    else if (i < 565248) { int j = i - 548864; cow[j] = (__bf16)ow[j]; }
  } else if (b < 2400) {
    int i = (b - 2208) * 256 + threadIdx.x;   // < 49152
    int l = i / 24576, r = i % 24576;
    int h = r / 6144, jd = r % 6144;
    int j = jd / 64, d = jd % 64;
    __bf16 v = (__bf16)0.0f;
    if (j < 80) v = (__bf16)wk[((size_t)l * 256 + h * 64 + d) * 336 + 256 + j];
    twk[i] = v;
  } else if (b < 14900) {
    // auxef, vectorized: 16 lanes per edge, f32x4 -> bf16x4
    int idx = (b - 2400) * 256 + threadIdx.x;   // e*16 + ln
    int e = idx >> 4, ln = idx & 15;
    f32x4 v = *reinterpret_cast<const f32x4*>(ef + (size_t)e * 64 + ln * 4);
    bf16x4 bv;
    bv[0] = (__bf16)v[0]; bv[1] = (__bf16)v[1];
    bv[2] = (__bf16)v[2]; bv[3] = (__bf16)v[3];
    *reinterpret_cast<bf16x4*>(aux + (size_t)e * 96 + ln * 4) = bv;
    if (ln < 4) {
      bf16x4 z;
      z[0] = (__bf16)0.0f; z[1] = (__bf16)0.0f; z[2] = (__bf16)0.0f; z[3] = (__bf16)0.0f;
      *reinterpret_cast<bf16x4*>(aux + (size_t)e * 96 + 80 + ln * 4) = z;
    }
  } else if (b < 14902) {
    int l = b - 14900;
    int n = threadIdx.x;
    const float* wq_l = wq + (size_t)l * 256 * 272;
    const float* teph_l = teph + l * 16;
    float s = wqb[l * 256 + n];
    for (int t = 0; t < 16; ++t) {
      float ph = teph_l[t];
      float q = (t == 0) ? ph : sinf(ph);
      s += q * wq_l[(size_t)n * 272 + 256 + t];
    }
    cq[l * 256 + n] = s;
  } else if (b < 27402) {
    int idx = (b - 14902) * 256 + threadIdx.x;   // e*16 + t
    int e = idx >> 4, t = idx & 15;
    float td = -tim[e];
    float wt = td * tew[t] + teph[t];
    float v = (t == 0) ? wt : __sinf(wt);
    aux[(size_t)e * 96 + 64 + t] = (__bf16)v;
  } else if (b < 28184) {
    int e = (b - 27402) * 256 + threadIdx.x;
    if (e < EE) atomicAdd(&cnt[ei[EE + e]], 1);
  } else {
    // ---- h0 = [node_feat|memory] @ in_w^T + in_b (weights read as f32) ----
    const int t = threadIdx.x;
    const int lane = t & 63;
    const int wv = t >> 6;
    const int c = lane & 15, g = lane >> 4;
    const int row0 = (b - 28184) * 64;
    const int colbase = wv * 64;

    {
      const int col4 = t & 63;
      const int rb = t >> 6;
      const bool useMem = (col4 >= 32);
      const int coff = (useMem ? (col4 - 32) : col4) * 4;
      const float* basep = useMem ? mem : nf;
      #pragma unroll
      for (int i = 0; i < 16; ++i) {
        const int row = rb + i * 4;
        int grow = row0 + row; if (grow >= NN) grow = NN - 1;
        f32x4 v = *reinterpret_cast<const f32x4*>(basep + (size_t)grow * 128 + coff);
        bf16x4 bv;
        bv[0] = (__bf16)v[0]; bv[1] = (__bf16)v[1];
        bv[2] = (__bf16)v[2]; bv[3] = (__bf16)v[3];
        *reinterpret_cast<bf16x4*>(&As[row][col4 * 4]) = bv;
      }
    }
    __syncthreads();

    const float* Bp[4];
    #pragma unroll
    for (int ct = 0; ct < 4; ++ct)
      Bp[ct] = inw + (size_t)(colbase + ct * 16 + c) * 256;

    f32x4 acc[4][4];
    #pragma unroll
    for (int rt = 0; rt < 4; ++rt)
      for (int ct = 0; ct < 4; ++ct)
        for (int r = 0; r < 4; ++r) acc[rt][ct][r] = 0.0f;

    #pragma unroll
    for (int ks = 0; ks < 8; ++ks) {
      const int k = ks * 32 + g * 8;
      bf16x8 a[4], bb[4];
      #pragma unroll
      for (int rt = 0; rt < 4; ++rt)
        a[rt] = *reinterpret_cast<const bf16x8*>(&As[rt * 16 + c][k]);
      #pragma unroll
      for (int ct = 0; ct < 4; ++ct) bb[ct] = cvt8(Bp[ct] + k);
      #pragma unroll
      for (int rt = 0; rt < 4; ++rt)
        #pragma unroll
        for (int ct = 0; ct < 4; ++ct)
          acc[rt][ct] = __builtin_amdgcn_mfma_f32_16x16x32_bf16(a[rt], bb[ct], acc[rt][ct], 0, 0, 0);
    }
    __syncthreads();

    #pragma unroll
    for (int ct = 0; ct < 4; ++ct) {
      const float bv = inb[colbase + ct * 16 + c];
      #pragma unroll
      for (int rt = 0; rt < 4; ++rt)
        #pragma unroll
        for (int rr = 0; rr < 4; ++rr)
          As[rt * 16 + g * 4 + rr][colbase + ct * 16 + c] = (__bf16)(acc[rt][ct][rr] + bv);
    }
    #pragma unroll
    for (int i = 0; i < 8; ++i) {
      const int r = i * 8 + (lane >> 3);
      const int ck = lane & 7;
      bf16x8 v = *reinterpret_cast<const bf16x8*>(&As[r][colbase + ck * 8]);
      const int row = row0 + r;
      if (row < NN)
        *reinterpret_cast<bf16x8*>(hb + (size_t)row * 256 + colbase + ck * 8) = v;
    }
  }
}

__global__ __launch_bounds__(256) void k_blksum(const int* __restrict__ wp, int* __restrict__ bsum) {
  __shared__ int red[256];
  int i = blockIdx.x * 256 + threadIdx.x;
  int v = (i < NN) ? wp[i] : 0;
  red[threadIdx.x] = v;
  __syncthreads();
  for (int off = 128; off > 0; off >>= 1) {
    if (threadIdx.x < off) red[threadIdx.x] += red[threadIdx.x + off];
    __syncthreads();
  }
  if (threadIdx.x == 0) bsum[blockIdx.x] = red[0];
}

__global__ __launch_bounds__(256) void k_scanb(int* __restrict__ bsum, int nb) {
  __shared__ int s[256];
  int t = threadIdx.x;
  int v = (t < nb) ? bsum[t] : 0;
  s[t] = v;
  __syncthreads();
  for (int off = 1; off < 256; off <<= 1) {
    int u = (t >= off) ? s[t - off] : 0;
    __syncthreads();
    s[t] += u;
    __syncthreads();
  }
  if (t < nb) bsum[t] = s[t] - v;
}

__global__ __launch_bounds__(256) void k_scanc(int* __restrict__ wp,
                                               const int* __restrict__ bsum,
                                               int* __restrict__ rowptr) {
  __shared__ int s[256];
  int i = blockIdx.x * 256 + threadIdx.x;
  int t = threadIdx.x;
  int v = (i < NN) ? wp[i] : 0;
  s[t] = v;
  __syncthreads();
  for (int off = 1; off < 256; off <<= 1) {
    int u = (t >= off) ? s[t - off] : 0;
    __syncthreads();
    s[t] += u;
    __syncthreads();
  }
  int excl = s[t] - v + bsum[blockIdx.x];
  if (i < NN) { rowptr[i] = excl; wp[i] = excl; }
  if (i == 0) rowptr[NN] = EE;
}

__global__ __launch_bounds__(256) void k_fill(const int* __restrict__ ei,
                                              int* __restrict__ wp,
                                              int* __restrict__ bucket) {
  int e = blockIdx.x * 256 + threadIdx.x;
  if (e < EE) {
    int d = ei[EE + e];
    int pos = atomicAdd(&wp[d], 1);
    bucket[pos] = e;
  }
}

// ---------------- Qn/Kn GEMMs + fused per-head G (+ fused auxte for l=1) ----------------
// blocks [0,nbq): GEMM; blocks [nbq, nbq+12500): aux time-encoding refresh.

__global__ __launch_bounds__(256, 2) void k_qkn(const __bf16* __restrict__ hb,
                                                const __bf16* __restrict__ wq_l,
                                                const __bf16* __restrict__ wk_l,
                                                const float* __restrict__ cq,
                                                const float* __restrict__ bk_l,
                                                const __bf16* __restrict__ twk_l,
                                                __bf16* __restrict__ Qn,
                                                __bf16* __restrict__ Kn,
                                                __bf16* __restrict__ G,
                                                const float* __restrict__ tim,
                                                const float* __restrict__ tew_l,
                                                const float* __restrict__ teph_l,
                                                __bf16* __restrict__ aux,
                                                int nbq) {
  __shared__ __bf16 As[64][264];
  __shared__ __bf16 tile[4][64][84];
  if (blockIdx.x >= nbq) {
    int idx = (blockIdx.x - nbq) * 256 + threadIdx.x;   // e*16 + t
    int e = idx >> 4, t = idx & 15;
    float td = -tim[e];
    float wt = td * tew_l[t] + teph_l[t];
    float v = (t == 0) ? wt : __sinf(wt);
    aux[(size_t)e * 96 + 64 + t] = (__bf16)v;
    return;
  }
  const int lane = threadIdx.x & 63;
  const int wv = threadIdx.x >> 6;
  const int c = lane & 15, g = lane >> 4;
  const int row0 = blockIdx.x * 64;
  const int colbase = wv * 64;

  {
    #pragma unroll
    for (int i = 0; i < 8; ++i) {
      const int cc = threadIdx.x + i * 256;
      const int row = cc >> 5;
      const int col8 = cc & 31;
      int grow = row0 + row; if (grow >= NN) grow = NN - 1;
      *reinterpret_cast<bf16x8*>(&As[row][col8 * 8]) =
          ld8(hb + (size_t)grow * 256 + col8 * 8);
    }
  }
  __syncthreads();

  f32x4 acc[4][4];

  // ---- pass 1: Q ----
  #pragma unroll
  for (int rt = 0; rt < 4; ++rt)
    for (int ct = 0; ct < 4; ++ct)
      for (int r = 0; r < 4; ++r) acc[rt][ct][r] = 0.0f;
  {
    const __bf16* Bp[4];
    #pragma unroll
    for (int ct = 0; ct < 4; ++ct)
      Bp[ct] = wq_l + (size_t)(colbase + ct * 16 + c) * 272;
    #pragma unroll
    for (int ks = 0; ks < 8; ++ks) {
      const int k = ks * 32 + g * 8;
      bf16x8 a[4], b[4];
      #pragma unroll
      for (int rt = 0; rt < 4; ++rt)
        a[rt] = *reinterpret_cast<const bf16x8*>(&As[rt * 16 + c][k]);
      #pragma unroll
      for (int ct = 0; ct < 4; ++ct) b[ct] = ld8(Bp[ct] + k);
      #pragma unroll
      for (int rt = 0; rt < 4; ++rt)
        #pragma unroll
        for (int ct = 0; ct < 4; ++ct)
          acc[rt][ct] = __builtin_amdgcn_mfma_f32_16x16x32_bf16(a[rt], b[ct], acc[rt][ct], 0, 0, 0);
    }
  }
  #pragma unroll
  for (int ct = 0; ct < 4; ++ct) {
    const float cqv = cq[colbase + ct * 16 + c];
    #pragma unroll
    for (int rt = 0; rt < 4; ++rt)
      #pragma unroll
      for (int rr = 0; rr < 4; ++rr)
        tile[wv][rt * 16 + g * 4 + rr][ct * 16 + c] = (__bf16)(acc[rt][ct][rr] + cqv);
  }
  #pragma unroll
  for (int i = 0; i < 8; ++i) {
    const int r = i * 8 + (lane >> 3);
    const int ck = lane & 7;
    bf16x8 v = *reinterpret_cast<const bf16x8*>(&tile[wv][r][ck * 8]);
    const int row = row0 + r;
    if (row < NN)
      *reinterpret_cast<bf16x8*>(Qn + (size_t)row * 256 + colbase + ck * 8) = v;
  }

  // ---- fused G pass ----
  {
    f32x4 accg[4][5];
    #pragma unroll
    for (int rt = 0; rt < 4; ++rt)
      for (int ct = 0; ct < 5; ++ct)
        for (int r = 0; r < 4; ++r) accg[rt][ct][r] = 0.0f;
    const __bf16* Bp[5];
    #pragma unroll
    for (int ct = 0; ct < 5; ++ct)
      Bp[ct] = twk_l + (size_t)wv * 6144 + (size_t)(ct * 16 + c) * 64;
    #pragma unroll
    for (int ks = 0; ks < 2; ++ks) {
      const int k = ks * 32 + g * 8;
      bf16x8 a[4], b[5];
      #pragma unroll
      for (int rt = 0; rt < 4; ++rt)
        a[rt] = *reinterpret_cast<const bf16x8*>(&tile[wv][rt * 16 + c][k]);
      #pragma unroll
      for (int ct = 0; ct < 5; ++ct) b[ct] = ld8(Bp[ct] + k);
      #pragma unroll
      for (int rt = 0; rt < 4; ++rt)
        #pragma unroll
        for (int ct = 0; ct < 5; ++ct)
          accg[rt][ct] = __builtin_amdgcn_mfma_f32_16x16x32_bf16(a[rt], b[ct], accg[rt][ct], 0, 0, 0);
    }
    #pragma unroll
    for (int ct = 0; ct < 5; ++ct) {
      #pragma unroll
      for (int rt = 0; rt < 4; ++rt)
        #pragma unroll
        for (int rr = 0; rr < 4; ++rr)
          tile[wv][rt * 16 + g * 4 + rr][ct * 16 + c] = (__bf16)accg[rt][ct][rr];
    }
    #pragma unroll
    for (int i = 0; i < 10; ++i) {
      const int idx = i * 64 + lane;
      const int r = idx / 10;
      const int ck = idx % 10;
      bf16x8 v = *reinterpret_cast<const bf16x8*>(&tile[wv][r][ck * 8]);
      const int row = row0 + r;
      if (row < NN)
        *reinterpret_cast<bf16x8*>(G + (size_t)row * 320 + wv * 80 + ck * 8) = v;
    }
  }

  // ---- pass 2: K ----
  #pragma unroll
  for (int rt = 0; rt < 4; ++rt)
    for (int ct = 0; ct < 4; ++ct)
      for (int r = 0; r < 4; ++r) acc[rt][ct][r] = 0.0f;
  {
    const __bf16* Bp[4];
    #pragma unroll
    for (int ct = 0; ct < 4; ++ct)
      Bp[ct] = wk_l + (size_t)(colbase + ct * 16 + c) * 336;
    #pragma unroll
    for (int ks = 0; ks < 8; ++ks) {
      const int k = ks * 32 + g * 8;
      bf16x8 a[4], b[4];
      #pragma unroll
      for (int rt = 0; rt < 4; ++rt)
        a[rt] = *reinterpret_cast<const bf16x8*>(&As[rt * 16 + c][k]);
      #pragma unroll
      for (int ct = 0; ct < 4; ++ct) b[ct] = ld8(Bp[ct] + k);
      #pragma unroll
      for (int rt = 0; rt < 4; ++rt)
        #pragma unroll
        for (int ct = 0; ct < 4; ++ct)
          acc[rt][ct] = __builtin_amdgcn_mfma_f32_16x16x32_bf16(a[rt], b[ct], acc[rt][ct], 0, 0, 0);
    }
  }
  #pragma unroll
  for (int ct = 0; ct < 4; ++ct) {
    const float bkv = bk_l[colbase + ct * 16 + c];
    #pragma unroll
    for (int rt = 0; rt < 4; ++rt)
      #pragma unroll
      for (int rr = 0; rr < 4; ++rr)
        tile[wv][rt * 16 + g * 4 + rr][ct * 16 + c] = (__bf16)(acc[rt][ct][rr] + bkv);
  }
  #pragma unroll
  for (int i = 0; i < 8; ++i) {
    const int r = i * 8 + (lane >> 3);
    const int ck = lane & 7;
    bf16x8 v = *reinterpret_cast<const bf16x8*>(&tile[wv][r][ck * 8]);
    const int row = row0 + r;
    if (row < NN)
      *reinterpret_cast<bf16x8*>(Kn + (size_t)row * 256 + colbase + ck * 8) = v;
  }
}

// ---- fused score + CSR aggregate, chunk-4 + lane-parallel index prefetch ----
// (R9 configuration: 1 node/wave, 44 VGPR, occupancy ~41% -- proven optimum)

__global__ __launch_bounds__(256, 4) void k_sagg(const __bf16* __restrict__ hb,
                                                 const __bf16* __restrict__ aux,
                                                 const __bf16* __restrict__ G,
                                                 const __bf16* __restrict__ Qn,
                                                 const __bf16* __restrict__ Kn,
                                                 const int* __restrict__ ei,
                                                 const int* __restrict__ rowptr,
                                                 const int* __restrict__ bucket,
                                                 __bf16* __restrict__ maggH,
                                                 __bf16* __restrict__ maggX,
                                                 float* __restrict__ sfac) {
  const int lane = threadIdx.x & 63;
  const int wv = threadIdx.x >> 6;
  const int node = blockIdx.x * 4 + wv;
  const int beg = rowptr[node], end = rowptr[node + 1];
  const int deg = end - beg;
  const int c = lane & 15;
  const int grp = lane >> 4;

  float aH[4] = {0, 0, 0, 0};
  float aXv[4] = {0, 0, 0, 0};
  float aXs = 0.0f;
  float nrm = 0.0f;

  if (deg > 0) {
    const int iq = ei[EE + node];
    const __bf16* Qr = Qn + (size_t)iq * 256;
    const __bf16* Gr = G + (size_t)iq * 320;

    bf16x4 qv = ld4(Qr + lane * 4);
    bf16x4 gv = ld4(Gr + grp * 80 + c * 4);
    const float gs = (float)Gr[grp * 80 + 64 + c];

    // lane-parallel index prefetch (covers first 64 edges; deg>64 near-impossible)
    int eL = 0, sL = 0;
    const int degc = (deg < 64) ? deg : 64;
    if (lane < degc) eL = bucket[beg + lane];
    if (lane < degc) sL = ei[eL];

    for (int base = 0; base < deg; base += 4) {
      const int rem = deg - base;
      const int iA = base;
      const int iB = base + ((1 < rem) ? 1 : 0);
      const int iC = base + ((2 < rem) ? 2 : 0);
      const int iD = base + ((3 < rem) ? 3 : 0);
      int eA = __shfl(eL, (iA < 64) ? iA : 0, 64);
      int sA = __shfl(sL, (iA < 64) ? iA : 0, 64);
      int eB = __shfl(eL, (iB < 64) ? iB : 0, 64);
      int sB = __shfl(sL, (iB < 64) ? iB : 0, 64);
      int eC = __shfl(eL, (iC < 64) ? iC : 0, 64);
      int sC = __shfl(sL, (iC < 64) ? iC : 0, 64);
      int eD = __shfl(eL, (iD < 64) ? iD : 0, 64);
      int sD = __shfl(sL, (iD < 64) ? iD : 0, 64);
      if (iD >= 64) {                      // wave-uniform; rare tail
        if (iA >= 64) { eA = bucket[beg + iA]; sA = ei[eA]; }
        if (iB >= 64) { eB = bucket[beg + iB]; sB = ei[eB]; }
        if (iC >= 64) { eC = bucket[beg + iC]; sC = ei[eC]; }
        eD = bucket[beg + iD]; sD = ei[eD];
      }

      bf16x4 kvA = ld4(Kn + (size_t)sA * 256 + lane * 4);
      bf16x4 kvB = ld4(Kn + (size_t)sB * 256 + lane * 4);
      bf16x4 kvC = ld4(Kn + (size_t)sC * 256 + lane * 4);
      bf16x4 kvD = ld4(Kn + (size_t)sD * 256 + lane * 4);
      bf16x4 hvA = ld4(hb + (size_t)sA * 256 + lane * 4);
      bf16x4 hvB = ld4(hb + (size_t)sB * 256 + lane * 4);
      bf16x4 hvC = ld4(hb + (size_t)sC * 256 + lane * 4);
      bf16x4 hvD = ld4(hb + (size_t)sD * 256 + lane * 4);
      bf16x4 avA = ld4(aux + (size_t)eA * 96 + c * 4);
      bf16x4 avB = ld4(aux + (size_t)eB * 96 + c * 4);
      bf16x4 avC = ld4(aux + (size_t)eC * 96 + c * 4);
      bf16x4 avD = ld4(aux + (size_t)eD * 96 + c * 4);
      const float asA = (float)aux[(size_t)eA * 96 + 64 + c];
      const float asB = (float)aux[(size_t)eB * 96 + 64 + c];
      const float asC = (float)aux[(size_t)eC * 96 + 64 + c];
      const float asD = (float)aux[(size_t)eD * 96 + 64 + c];

      float pA = gs * asA, pB = gs * asB, pC = gs * asC, pD = gs * asD;
      #pragma unroll
      for (int j = 0; j < 4; ++j) {
        const float qj = (float)qv[j], gj = (float)gv[j];
        pA += qj * (float)kvA[j] + gj * (float)avA[j];
        pB += qj * (float)kvB[j] + gj * (float)avB[j];
        pC += qj * (float)kvC[j] + gj * (float)avC[j];
        pD += qj * (float)kvD[j] + gj * (float)avD[j];
      }
      #pragma unroll
      for (int m = 1; m <= 8; m <<= 1) {
        pA += __shfl_xor(pA, m, 64);
        pB += __shfl_xor(pB, m, 64);
        pC += __shfl_xor(pC, m, 64);
        pD += __shfl_xor(pD, m, 64);
      }
      float exA = __expf(fminf(5.0f, fmaxf(-5.0f, pA * 0.125f)));
      float exB = __expf(fminf(5.0f, fmaxf(-5.0f, pB * 0.125f)));
      float exC = __expf(fminf(5.0f, fmaxf(-5.0f, pC * 0.125f)));
      float exD = __expf(fminf(5.0f, fmaxf(-5.0f, pD * 0.125f)));
      exA += __shfl_xor(exA, 16, 64);
      exB += __shfl_xor(exB, 16, 64);
      exC += __shfl_xor(exC, 16, 64);
      exD += __shfl_xor(exD, 16, 64);
      exA += __shfl_xor(exA, 32, 64);
      exB += __shfl_xor(exB, 32, 64);
      exC += __shfl_xor(exC, 32, 64);
      exD += __shfl_xor(exD, 32, 64);
      const float aA = exA * 0.25f;
      const float aB = (1 < rem) ? exB * 0.25f : 0.0f;
      const float aC = (2 < rem) ? exC * 0.25f : 0.0f;
      const float aD = (3 < rem) ? exD * 0.25f : 0.0f;

      nrm += aA + aB + aC + aD;
      #pragma unroll
      for (int j = 0; j < 4; ++j)
        aH[j] += aA * (float)hvA[j] + aB * (float)hvB[j] +
                 aC * (float)hvC[j] + aD * (float)hvD[j];
      if (grp == 0) {
        #pragma unroll
        for (int j = 0; j < 4; ++j)
          aXv[j] += aA * (float)avA[j] + aB * (float)avB[j] +
                    aC * (float)avC[j] + aD * (float)avD[j];
      } else if (grp == 1) {
        aXs += aA * asA + aB * asB + aC * asC + aD * asD;
      }
    }
  }

  const float inv = 1.0f / (nrm + 1e-8f);
  bf16x4 oh;
  #pragma unroll
  for (int j = 0; j < 4; ++j) oh[j] = (__bf16)(aH[j] * inv);
  *reinterpret_cast<bf16x4*>(maggH + (size_t)node * 256 + lane * 4) = oh;
  if (grp == 0) {
    bf16x4 ox;
    #pragma unroll
    for (int j = 0; j < 4; ++j) ox[j] = (__bf16)(aXv[j] * inv);
    *reinterpret_cast<bf16x4*>(maggX + (size_t)node * 96 + c * 4) = ox;
  } else if (grp == 1) {
    maggX[(size_t)node * 96 + 64 + c] = (__bf16)(aXs * inv);
  } else if (grp == 2) {
    maggX[(size_t)node * 96 + 80 + c] = (__bf16)0.0f;
  }
  if (lane == 0) sfac[node] = nrm * inv;
}

// ---- small-workspace fallback: score-only (af) + separate aggregate ----

__global__ __launch_bounds__(256, 4) void k_score3(const __bf16* __restrict__ aux,
                                                   const __bf16* __restrict__ G,
                                                   const __bf16* __restrict__ Qn,
                                                   const __bf16* __restrict__ Kn,
                                                   const int* __restrict__ ei,
                                                   const int* __restrict__ rowptr,
                                                   const int* __restrict__ bucket,
                                                   float* __restrict__ af) {
  const int lane = threadIdx.x & 63;
  const int wv = threadIdx.x >> 6;
  const int node = blockIdx.x * 4 + wv;
  const int beg = rowptr[node], end = rowptr[node + 1];
  const int c = lane & 15;
  const int grp = lane >> 4;

  if (beg < end) {
    const int iq = ei[EE + node];
    const __bf16* Qr = Qn + (size_t)iq * 256;
    const __bf16* Gr = G + (size_t)iq * 320;

    bf16x4 qv = ld4(Qr + lane * 4);
    bf16x4 gv = ld4(Gr + grp * 80 + c * 4);
    const float gs = (float)Gr[grp * 80 + 64 + c];

    int e = bucket[beg];
    int s = ei[e];
    for (int i = beg; i < end; ++i) {
      const int en = (i + 1 < end) ? bucket[i + 1] : e;
      const int sn = ei[en];
      bf16x4 kv = ld4(Kn + (size_t)s * 256 + lane * 4);
      bf16x4 av = ld4(aux + (size_t)e * 96 + c * 4);
      float as = (float)aux[(size_t)e * 96 + 64 + c];

      float p = gs * as;
      #pragma unroll
      for (int j = 0; j < 4; ++j) {
        p += (float)qv[j] * (float)kv[j];
        p += (float)gv[j] * (float)av[j];
      }
      p += __shfl_xor(p, 1, 64);
      p += __shfl_xor(p, 2, 64);
      p += __shfl_xor(p, 4, 64);
      p += __shfl_xor(p, 8, 64);
      float sc = fminf(5.0f, fmaxf(-5.0f, p * 0.125f));
      float ex = __expf(sc);
      ex += __shfl_xor(ex, 16, 64);
      ex += __shfl_xor(ex, 32, 64);
      if (lane == 0) af[e] = ex * 0.25f;
      e = en; s = sn;
    }
  }
}

__global__ __launch_bounds__(256, 4) void k_magg(const __bf16* __restrict__ hb,
                                                 const __bf16* __restrict__ aux,
                                                 const int* __restrict__ ei,
                                                 const int* __restrict__ rowptr,
                                                 const int* __restrict__ bucket,
                                                 const float* __restrict__ af,
                                                 __bf16* __restrict__ maggH,
                                                 __bf16* __restrict__ maggX,
                                                 float* __restrict__ sfac) {
  const int lane = threadIdx.x & 63;
  const int wv = threadIdx.x >> 6;
  const int node = blockIdx.x * 4 + wv;
  const int beg = rowptr[node], end = rowptr[node + 1];

  float aH[4] = {0, 0, 0, 0};
  float aX[2] = {0, 0};
  float nrm = 0.0f;
  if (beg < end) {
    int e = bucket[beg];
    float a = af[e];
    int s = ei[e];
    for (int i = beg; i < end; ++i) {
      const int en = (i + 1 < end) ? bucket[i + 1] : e;
      const float an = af[en];
      const int sn = ei[en];
      bf16x4 hv = ld4(hb + (size_t)s * 256 + lane * 4);
      #pragma unroll
      for (int j = 0; j < 4; ++j) aH[j] += a * (float)hv[j];
      if (lane < 48) {
        bf16x2 xv = *reinterpret_cast<const bf16x2*>(aux + (size_t)e * 96 + lane * 2);
        aX[0] += a * (float)xv[0];
        aX[1] += a * (float)xv[1];
      }
      nrm += a;
      e = en; a = an; s = sn;
    }
  }
  const float inv = 1.0f / (nrm + 1e-8f);
  bf16x4 oh;
  #pragma unroll
  for (int j = 0; j < 4; ++j) oh[j] = (__bf16)(aH[j] * inv);
  *reinterpret_cast<bf16x4*>(maggH + (size_t)node * 256 + lane * 4) = oh;
  if (lane < 48) {
    bf16x2 ox;
    ox[0] = (__bf16)(aX[0] * inv);
    ox[1] = (__bf16)(aX[1] * inv);
    *reinterpret_cast<bf16x2*>(maggX + (size_t)node * 96 + lane * 2) = ox;
  }
  if (lane == 0) sfac[node] = nrm * inv;
}

// ---- fused V-GEMM + double layer-norm (+ fused out-GEMM on last layer) ----
// single full-width LDS buffer As[64][360]: cols 0..255 maggH (then hb, then
// h_new), cols 256..351 maggX. All MFMA A-operands come from LDS.

__global__ __launch_bounds__(256, 3) void k_vnorm(const __bf16* __restrict__ maggH,
                                                  const __bf16* __restrict__ maggX,
                                                  const float* __restrict__ sfac,
                                                  const __bf16* __restrict__ wv_l,
                                                  const float* __restrict__ bv_l,
                                                  __bf16* __restrict__ hb,
                                                  const float* __restrict__ aw,
                                                  const float* __restrict__ ab,
                                                  const float* __restrict__ lw,
                                                  const float* __restrict__ lb,
                                                  const __bf16* __restrict__ cow,
                                                  const float* __restrict__ obias,
                                                  float* __restrict__ outp,
                                                  int last) {
  __shared__ __bf16 As[64][360];
  __shared__ float redA[64][4];
  __shared__ float redB[64][4];
  const int t = threadIdx.x;
  const int lane = t & 63;
  const int wv = t >> 6;
  const int c = lane & 15, g = lane >> 4;
  const int row0 = blockIdx.x * 64;
  const int colbase = wv * 64;

  // ---- stage maggH (cols 0..255) + maggX (cols 256..351), coalesced ----
  #pragma unroll
  for (int i = 0; i < 8; ++i) {
    const int cc = t + i * 256;
    const int row = cc >> 5;
    const int col8 = cc & 31;
    int grow = row0 + row; if (grow >= NN) grow = NN - 1;
    *reinterpret_cast<bf16x8*>(&As[row][col8 * 8]) =
        ld8(maggH + (size_t)grow * 256 + col8 * 8);
  }
  #pragma unroll
  for (int i = 0; i < 3; ++i) {
    const int cc = t + i * 256;     // < 768 = 64 rows * 12 chunks
    const int row = cc / 12;
    const int col8 = cc % 12;
    int grow = row0 + row; if (grow >= NN) grow = NN - 1;
    *reinterpret_cast<bf16x8*>(&As[row][256 + col8 * 8]) =
        ld8(maggX + (size_t)grow * 96 + col8 * 8);
  }
  __syncthreads();

  const __bf16* Bp[4];
  #pragma unroll
  for (int ct = 0; ct < 4; ++ct)
    Bp[ct] = wv_l + (size_t)(colbase + ct * 16 + c) * 336;

  f32x4 acc[4][4];
  #pragma unroll
  for (int rt = 0; rt < 4; ++rt)
    for (int ct = 0; ct < 4; ++ct)
      for (int r = 0; r < 4; ++r) acc[rt][ct][r] = 0.0f;

  #pragma unroll
  for (int ks = 0; ks < 8; ++ks) {
    const int k = ks * 32 + g * 8;
    bf16x8 a[4], b[4];
    #pragma unroll
    for (int rt = 0; rt < 4; ++rt)
      a[rt] = *reinterpret_cast<const bf16x8*>(&As[rt * 16 + c][k]);
    #pragma unroll
    for (int ct = 0; ct < 4; ++ct) b[ct] = ld8(Bp[ct] + k);
    #pragma unroll
    for (int rt = 0; rt < 4; ++rt)
      #pragma unroll
      for (int ct = 0; ct < 4; ++ct)
        acc[rt][ct] = __builtin_amdgcn_mfma_f32_16x16x32_bf16(a[rt], b[ct], acc[rt][ct], 0, 0, 0);
  }
  const bf16x8 bz = zero8();
  #pragma unroll
  for (int ks = 0; ks < 3; ++ks) {
    const int kk = ks * 32 + g * 8;
    bf16x8 a[4], b[4];
    #pragma unroll
    for (int rt = 0; rt < 4; ++rt)
      a[rt] = *reinterpret_cast<const bf16x8*>(&As[rt * 16 + c][256 + kk]);
    #pragma unroll
    for (int ct = 0; ct < 4; ++ct)
      b[ct] = (kk < 80) ? ld8(Bp[ct] + 256 + kk) : bz;
    #pragma unroll
    for (int rt = 0; rt < 4; ++rt)
      #pragma unroll
      for (int ct = 0; ct < 4; ++ct)
        acc[rt][ct] = __builtin_amdgcn_mfma_f32_16x16x32_bf16(a[rt], b[ct], acc[rt][ct], 0, 0, 0);
  }

  // ---- re-stage As cols 0..255 with hb residual ----
  __syncthreads();
  #pragma unroll
  for (int i = 0; i < 8; ++i) {
    const int cc = t + i * 256;
    const int row = cc >> 5;
    const int col8 = cc & 31;
    int grow = row0 + row; if (grow >= NN) grow = NN - 1;
    *reinterpret_cast<bf16x8*>(&As[row][col8 * 8]) =
        ld8(hb + (size_t)grow * 256 + col8 * 8);
  }
  __syncthreads();

  float sf[4][4];
  #pragma unroll
  for (int rt = 0; rt < 4; ++rt)
    #pragma unroll
    for (int rr = 0; rr < 4; ++rr) {
      int row = row0 + rt * 16 + g * 4 + rr; if (row >= NN) row = NN - 1;
      sf[rt][rr] = sfac[row];
    }
  float bvv[4], awv[4], abv[4], lwv[4], lbv[4];
  #pragma unroll
  for (int ct = 0; ct < 4; ++ct) {
    const int col = colbase + ct * 16 + c;
    bvv[ct] = bv_l[col];
    awv[ct] = aw[col]; abv[ct] = ab[col];
    lwv[ct] = lw[col]; lbv[ct] = lb[col];
  }
  #pragma unroll
  for (int rt = 0; rt < 4; ++rt)
    #pragma unroll
    for (int ct = 0; ct < 4; ++ct)
      #pragma unroll
      for (int rr = 0; rr < 4; ++rr)
        acc[rt][ct][rr] += sf[rt][rr] * bvv[ct];

  // ---- LN1 mean ----
  float s1[4][4];
  #pragma unroll
  for (int rt = 0; rt < 4; ++rt)
    #pragma unroll
    for (int rr = 0; rr < 4; ++rr) {
      float s = 0.0f;
      #pragma unroll
      for (int ct = 0; ct < 4; ++ct) s += acc[rt][ct][rr];
      #pragma unroll
      for (int m = 1; m < 16; m <<= 1) s += __shfl_xor(s, m, 64);
      s1[rt][rr] = s;
    }
  if (c == 0)
    #pragma unroll
    for (int rt = 0; rt < 4; ++rt)
      #pragma unroll
      for (int rr = 0; rr < 4; ++rr)
        redA[rt * 16 + g * 4 + rr][wv] = s1[rt][rr];
  __syncthreads();
  float mean1[4][4];
  #pragma unroll
  for (int rt = 0; rt < 4; ++rt)
    #pragma unroll
    for (int rr = 0; rr < 4; ++rr) {
      const int r = rt * 16 + g * 4 + rr;
      mean1[rt][rr] = (redA[r][0] + redA[r][1] + redA[r][2] + redA[r][3]) * (1.0f / 256.0f);
    }
  // ---- LN1 var ----
  #pragma unroll
  for (int rt = 0; rt < 4; ++rt)
    #pragma unroll
    for (int rr = 0; rr < 4; ++rr) {
      float q = 0.0f;
      #pragma unroll
      for (int ct = 0; ct < 4; ++ct) {
        float d = acc[rt][ct][rr] - mean1[rt][rr];
        q += d * d;
      }
      #pragma unroll
      for (int m = 1; m < 16; m <<= 1) q += __shfl_xor(q, m, 64);
      s1[rt][rr] = q;
    }
  if (c == 0)
    #pragma unroll
    for (int rt = 0; rt < 4; ++rt)
      #pragma unroll
      for (int rr = 0; rr < 4; ++rr)
        redB[rt * 16 + g * 4 + rr][wv] = s1[rt][rr];
  __syncthreads();
  float rstd1[4][4];
  #pragma unroll
  for (int rt = 0; rt < 4; ++rt)
    #pragma unroll
    for (int rr = 0; rr < 4; ++rr) {
      const int r = rt * 16 + g * 4 + rr;
      float v = (redB[r][0] + redB[r][1] + redB[r][2] + redB[r][3]) * (1.0f / 256.0f);
      rstd1[rt][rr] = rsqrtf(v + 1e-5f);
    }

  // ---- y = hb + LN1(x)*aw + ab ; LN2 mean ----
  #pragma unroll
  for (int rt = 0; rt < 4; ++rt)
    #pragma unroll
    for (int rr = 0; rr < 4; ++rr) {
      const int r = rt * 16 + g * 4 + rr;
      float s = 0.0f;
      #pragma unroll
      for (int ct = 0; ct < 4; ++ct) {
        float hbv = (float)As[r][colbase + ct * 16 + c];
        float y = hbv + (acc[rt][ct][rr] - mean1[rt][rr]) * rstd1[rt][rr] * awv[ct] + abv[ct];
        acc[rt][ct][rr] = y;
        s += y;
      }
      #pragma unroll
      for (int m = 1; m < 16; m <<= 1) s += __shfl_xor(s, m, 64);
      s1[rt][rr] = s;
    }
  if (c == 0)
    #pragma unroll
    for (int rt = 0; rt < 4; ++rt)
      #pragma unroll
      for (int rr = 0; rr < 4; ++rr)
        redA[rt * 16 + g * 4 + rr][wv] = s1[rt][rr];
  __syncthreads();
  float mean2[4][4];
  #pragma unroll
  for (int rt = 0; rt < 4; ++rt)
    #pragma unroll
    for (int rr = 0; rr < 4; ++rr) {
      const int r = rt * 16 + g * 4 + rr;
      mean2[rt][rr] = (redA[r][0] + redA[r][1] + redA[r][2] + redA[r][3]) * (1.0f / 256.0f);
    }
  // ---- LN2 var ----
  #pragma unroll
  for (int rt = 0; rt < 4; ++rt)
    #pragma unroll
    for (int rr = 0; rr < 4; ++rr) {
      float q = 0.0f;
      #pragma unroll
      for (int ct = 0; ct < 4; ++ct) {
        float d = acc[rt][ct][rr] - mean2[rt][rr];
        q += d * d;
      }
      #pragma unroll
      for (int m = 1; m < 16; m <<= 1) q += __shfl_xor(q, m, 64);
      s1[rt][rr] = q;
    }
  if (c == 0)
    #pragma unroll
    for (int rt = 0; rt < 4; ++rt)
      #pragma unroll
      for (int rr = 0; rr < 4; ++rr)
        redB[rt * 16 + g * 4 + rr][wv] = s1[rt][rr];
  __syncthreads();
  #pragma unroll
  for (int rt = 0; rt < 4; ++rt)
    #pragma unroll
    for (int rr = 0; rr < 4; ++rr) {
      const int r = rt * 16 + g * 4 + rr;
      float v = (redB[r][0] + redB[r][1] + redB[r][2] + redB[r][3]) * (1.0f / 256.0f);
      const float rstd2 = rsqrtf(v + 1e-5f);
      #pragma unroll
      for (int ct = 0; ct < 4; ++ct)
        As[r][colbase + ct * 16 + c] =
            (__bf16)((acc[rt][ct][rr] - mean2[rt][rr]) * rstd2 * lwv[ct] + lbv[ct]);
    }
  __syncthreads();

  if (!last) {
    // coalesced writeback of new hb
    #pragma unroll
    for (int i = 0; i < 8; ++i) {
      const int cc = t + i * 256;
      const int row = cc >> 5;
      const int col8 = cc & 31;
      const int grow = row0 + row;
      if (grow < NN)
        *reinterpret_cast<bf16x8*>(hb + (size_t)grow * 256 + col8 * 8) =
            *reinterpret_cast<const bf16x8*>(&As[row][col8 * 8]);
    }
  } else {
    // fused out = gelu(h_new @ out_w^T + out_b); h_new lives in As
    const __bf16* Bop = cow + (size_t)(wv * 16 + c) * 256;
    f32x4 acc2[4];
    #pragma unroll
    for (int rt = 0; rt < 4; ++rt)
      for (int rr = 0; rr < 4; ++rr) acc2[rt][rr] = 0.0f;
    #pragma unroll
    for (int ks = 0; ks < 8; ++ks) {
      const int k = ks * 32 + g * 8;
      bf16x8 bfrag = ld8(Bop + k);
      #pragma unroll
      for (int rt = 0; rt < 4; ++rt) {
        bf16x8 afrag = *reinterpret_cast<const bf16x8*>(&As[rt * 16 + c][k]);
        acc2[rt] = __builtin_amdgcn_mfma_f32_16x16x32_bf16(afrag, bfrag, acc2[rt], 0, 0, 0);
      }
    }
    const int col = wv * 16 + c;
    const float bo = obias[col];
    #pragma unroll
    for (int rt = 0; rt < 4; ++rt)
      #pragma unroll
      for (int rr = 0; rr < 4; ++rr) {
        const int row = row0 + rt * 16 + g * 4 + rr;
        if (row < NN) {
          float x = acc2[rt][rr] + bo;
          outp[(size_t)row * 64 + col] = 0.5f * x * (1.0f + erff(x * 0.70710678118654752f));
        }
      }
  }
}

// ---------------- launcher ----------------

extern "C" void kernel_launch(void* const* d_in, const int* in_sizes, int n_in,
                              void* d_out, int out_size, void* d_ws, size_t ws_size,
                              hipStream_t stream) {
  (void)in_sizes; (void)n_in; (void)out_size;
  const float* nf   = (const float*)d_in[0];
  const float* mem  = (const float*)d_in[1];
  const int*   ei   = (const int*)d_in[2];
  const float* ef   = (const float*)d_in[3];
  const float* tim  = (const float*)d_in[4];
  const float* inw  = (const float*)d_in[5];
  const float* inb  = (const float*)d_in[6];
  const float* tew  = (const float*)d_in[7];
  const float* teph = (const float*)d_in[8];
  const float* wq   = (const float*)d_in[9];
  const float* wqb  = (const float*)d_in[10];
  const float* wk   = (const float*)d_in[11];
  const float* wkb  = (const float*)d_in[12];
  const float* wvw  = (const float*)d_in[13];
  const float* wvb  = (const float*)d_in[14];
  const float* alw  = (const float*)d_in[15];
  const float* alb  = (const float*)d_in[16];
  const float* lnw  = (const float*)d_in[17];
  const float* lnb  = (const float*)d_in[18];
  const float* ow   = (const float*)d_in[19];
  const float* ob   = (const float*)d_in[20];
  float* out = (float*)d_out;

  char* ws = (char*)d_ws;
  // Fused k_sagg reads G while writing maggH/maggX -> they must be disjoint.
  // That needs ~186.7 MB; fall back to split score+aggregate (aliased layout) otherwise.
  const bool big = ws_size >= 186700000ULL;

  __bf16* hb    = (__bf16*)(ws + 0);            // N*256 bf16  = 25,600,000
  __bf16* aux   = (__bf16*)(ws + 25600000);     // E*96 bf16   = 38,400,000
  __bf16* Qn    = (__bf16*)(ws + 64000000);     // N*256 bf16  = 25,600,000
  __bf16* Kn    = (__bf16*)(ws + 89600000);     // N*256 bf16  = 25,600,000
  __bf16* G     = (__bf16*)(ws + 115200000);    // N*320 bf16  = 32,000,000 -> ends 147,200,000
  // big: magg after G (disjoint). small: magg aliases G (legal: split kernels, disjoint in time)
  __bf16* maggH = (__bf16*)(ws + (big ? 147200000 : 115200000));   // N*256 bf16
  __bf16* maggX = (__bf16*)(ws + (big ? 172800000 : 140800000));   // N*96 bf16
  const size_t o_tail = big ? 182400000 : 150400000;
  float*  sfac  = (float*) (ws + o_tail);             // N f32
  float*  af    = (float*) (ws + o_tail + 200000);    // E f32 (small path only)
  int*    rowptr= (int*)   (ws + o_tail + 1800000);   // (N+1) int
  int*    wp    = (int*)   (ws + o_tail + 2000192);   // N int
  int*    bucket= (int*)   (ws + o_tail + 2200192);   // E int
  float*  cq    = (float*) (ws + o_tail + 3000192);   // 2*256 f32
  int*    bsum  = (int*)   (ws + o_tail + 3002240);   // 196 int
  __bf16* cinw  = (__bf16*)(ws + o_tail + 3003264);   // 131,072
  __bf16* cwq   = (__bf16*)(ws + o_tail + 3134336);   // 278,528
  __bf16* cwk   = (__bf16*)(ws + o_tail + 3412864);   // 344,064
  __bf16* cwv   = (__bf16*)(ws + o_tail + 3756928);   // 344,064
  __bf16* cow   = (__bf16*)(ws + o_tail + 4100992);   // 32,768
  __bf16* twk   = (__bf16*)(ws + o_tail + 4133760);   // 98,304 -> end o_tail+4,232,064

  const int NB = (NN + 255) / 256;   // 196
  const int NBQ = (NN + 63) / 64;    // 782
  hipMemsetAsync(wp, 0, NN * 4, stream);
  // prep grid: 28184 base sections + 782 h0 blocks
  k_prep<<<28966, 256, 0, stream>>>(inw, wq, wk, wvw, ow, ef, tim, tew, teph, wqb, ei,
                                    nf, mem, inb,
                                    cinw, cwq, cwk, cwv, cow, twk, aux, cq, wp, hb);
  k_blksum<<<NB, 256, 0, stream>>>(wp, bsum);
  k_scanb<<<1, 256, 0, stream>>>(bsum, NB);
  k_scanc<<<NB, 256, 0, stream>>>(wp, bsum, rowptr);
  k_fill<<<(EE + 255) / 256, 256, 0, stream>>>(ei, wp, bucket);

  for (int l = 0; l < 2; ++l) {
    const __bf16* wq_l = cwq + (size_t)l * 256 * 272;
    const __bf16* wk_l = cwk + (size_t)l * 256 * 336;
    const __bf16* wv_l = cwv + (size_t)l * 256 * 336;
    // l=1: fuse the aux time-encoding refresh into the qkn dispatch
    const int grid_qkn = (l == 0) ? NBQ : (NBQ + EE * 16 / 256);
    k_qkn<<<grid_qkn, 256, 0, stream>>>(hb, wq_l, wk_l, cq + l * 256, wkb + l * 256,
                                        twk + (size_t)l * 24576, Qn, Kn, G,
                                        tim, tew + l * 16, teph + l * 16, aux, NBQ);
    if (big) {
      k_sagg<<<NN / 4, 256, 0, stream>>>(hb, aux, G, Qn, Kn, ei, rowptr, bucket,
                                         maggH, maggX, sfac);
    } else {
      k_score3<<<NN / 4, 256, 0, stream>>>(aux, G, Qn, Kn, ei, rowptr, bucket, af);
      k_magg<<<NN / 4, 256, 0, stream>>>(hb, aux, ei, rowptr, bucket, af, maggH, maggX, sfac);
    }
    k_vnorm<<<(NN + 63) / 64, 256, 0, stream>>>(maggH, maggX, sfac, wv_l, wvb + l * 256, hb,
                                                alw + l * 256, alb + l * 256,
                                                lnw + l * 256, lnb + l * 256,
                                                cow, ob, out, (l == 1) ? 1 : 0);
  }
}

// Round 13
// 518.676 us; speedup vs baseline: 1.0460x; 1.0460x over previous
//
#include <hip/hip_runtime.h>
#include <hip/hip_bf16.h>
#include <math.h>

#define NN 50000
#define EE 200000

typedef __bf16 bf16x8 __attribute__((ext_vector_type(8)));
typedef __bf16 bf16x4 __attribute__((ext_vector_type(4)));
typedef __bf16 bf16x2 __attribute__((ext_vector_type(2)));
typedef float f32x4 __attribute__((ext_vector_type(4)));

static __device__ __forceinline__ bf16x8 ld8(const __bf16* p) {
  return *reinterpret_cast<const bf16x8*>(p);
}
static __device__ __forceinline__ bf16x4 ld4(const __bf16* p) {
  return *reinterpret_cast<const bf16x4*>(p);
}
static __device__ __forceinline__ bf16x8 zero8() {
  bf16x8 z;
  #pragma unroll
  for (int j = 0; j < 8; ++j) z[j] = (__bf16)0.0f;
  return z;
}

// ---------------- fused prep: cvta | wt | auxef | cq2 | auxte(l0) | hist ----------------
// block ranges: [0,2208) cvta, [2208,2400) wt, [2400,14900) auxef (16 edges/block,
// vectorized), [14900,14902) cq2, [14902,27402) auxte l0, [27402,28184) hist

__global__ __launch_bounds__(256) void k_prep(const float* __restrict__ inw,
                                              const float* __restrict__ wq,
                                              const float* __restrict__ wk,
                                              const float* __restrict__ wvw,
                                              const float* __restrict__ ow,
                                              const float* __restrict__ ef,
                                              const float* __restrict__ tim,
                                              const float* __restrict__ tew,
                                              const float* __restrict__ teph,
                                              const float* __restrict__ wqb,
                                              const int* __restrict__ ei,
                                              __bf16* __restrict__ cinw,
                                              __bf16* __restrict__ cwq,
                                              __bf16* __restrict__ cwk,
                                              __bf16* __restrict__ cwv,
                                              __bf16* __restrict__ cow,
                                              __bf16* __restrict__ twk,
                                              __bf16* __restrict__ aux,
                                              float* __restrict__ cq,
                                              int* __restrict__ cnt) {
  const int b = blockIdx.x;
  if (b < 2208) {
    int i = b * 256 + threadIdx.x;
    if (i < 65536) cinw[i] = (__bf16)inw[i];
    else if (i < 204800) { int j = i - 65536;  cwq[j] = (__bf16)wq[j]; }
    else if (i < 376832) { int j = i - 204800; cwk[j] = (__bf16)wk[j]; }
    else if (i < 548864) { int j = i - 376832; cwv[j] = (__bf16)wvw[j]; }
    else if (i < 565248) { int j = i - 548864; cow[j] = (__bf16)ow[j]; }
  } else if (b < 2400) {
    int i = (b - 2208) * 256 + threadIdx.x;   // < 49152
    int l = i / 24576, r = i % 24576;
    int h = r / 6144, jd = r % 6144;
    int j = jd / 64, d = jd % 64;
    __bf16 v = (__bf16)0.0f;
    if (j < 80) v = (__bf16)wk[((size_t)l * 256 + h * 64 + d) * 336 + 256 + j];
    twk[i] = v;
  } else if (b < 14900) {
    // auxef, vectorized: 16 lanes per edge, f32x4 -> bf16x4
    int idx = (b - 2400) * 256 + threadIdx.x;   // e*16 + ln
    int e = idx >> 4, ln = idx & 15;
    f32x4 v = *reinterpret_cast<const f32x4*>(ef + (size_t)e * 64 + ln * 4);
    bf16x4 bv;
    bv[0] = (__bf16)v[0]; bv[1] = (__bf16)v[1];
    bv[2] = (__bf16)v[2]; bv[3] = (__bf16)v[3];
    *reinterpret_cast<bf16x4*>(aux + (size_t)e * 96 + ln * 4) = bv;
    if (ln < 4) {
      bf16x4 z;
      z[0] = (__bf16)0.0f; z[1] = (__bf16)0.0f; z[2] = (__bf16)0.0f; z[3] = (__bf16)0.0f;
      *reinterpret_cast<bf16x4*>(aux + (size_t)e * 96 + 80 + ln * 4) = z;
    }
  } else if (b < 14902) {
    int l = b - 14900;
    int n = threadIdx.x;
    const float* wq_l = wq + (size_t)l * 256 * 272;
    const float* teph_l = teph + l * 16;
    float s = wqb[l * 256 + n];
    for (int t = 0; t < 16; ++t) {
      float ph = teph_l[t];
      float q = (t == 0) ? ph : sinf(ph);
      s += q * wq_l[(size_t)n * 272 + 256 + t];
    }
    cq[l * 256 + n] = s;
  } else if (b < 27402) {
    int idx = (b - 14902) * 256 + threadIdx.x;   // e*16 + t
    int e = idx >> 4, t = idx & 15;
    float td = -tim[e];
    float wt = td * tew[t] + teph[t];
    float v = (t == 0) ? wt : __sinf(wt);
    aux[(size_t)e * 96 + 64 + t] = (__bf16)v;
  } else {
    int e = (b - 27402) * 256 + threadIdx.x;
    if (e < EE) atomicAdd(&cnt[ei[EE + e]], 1);
  }
}

__global__ __launch_bounds__(256) void k_blksum(const int* __restrict__ wp, int* __restrict__ bsum) {
  __shared__ int red[256];
  int i = blockIdx.x * 256 + threadIdx.x;
  int v = (i < NN) ? wp[i] : 0;
  red[threadIdx.x] = v;
  __syncthreads();
  for (int off = 128; off > 0; off >>= 1) {
    if (threadIdx.x < off) red[threadIdx.x] += red[threadIdx.x + off];
    __syncthreads();
  }
  if (threadIdx.x == 0) bsum[blockIdx.x] = red[0];
}

__global__ __launch_bounds__(256) void k_scanb(int* __restrict__ bsum, int nb) {
  __shared__ int s[256];
  int t = threadIdx.x;
  int v = (t < nb) ? bsum[t] : 0;
  s[t] = v;
  __syncthreads();
  for (int off = 1; off < 256; off <<= 1) {
    int u = (t >= off) ? s[t - off] : 0;
    __syncthreads();
    s[t] += u;
    __syncthreads();
  }
  if (t < nb) bsum[t] = s[t] - v;
}

__global__ __launch_bounds__(256) void k_scanc(int* __restrict__ wp,
                                               const int* __restrict__ bsum,
                                               int* __restrict__ rowptr) {
  __shared__ int s[256];
  int i = blockIdx.x * 256 + threadIdx.x;
  int t = threadIdx.x;
  int v = (i < NN) ? wp[i] : 0;
  s[t] = v;
  __syncthreads();
  for (int off = 1; off < 256; off <<= 1) {
    int u = (t >= off) ? s[t - off] : 0;
    __syncthreads();
    s[t] += u;
    __syncthreads();
  }
  int excl = s[t] - v + bsum[blockIdx.x];
  if (i < NN) { rowptr[i] = excl; wp[i] = excl; }
  if (i == 0) rowptr[NN] = EE;
}

__global__ __launch_bounds__(256) void k_fill(const int* __restrict__ ei,
                                              int* __restrict__ wp,
                                              int* __restrict__ bucket) {
  int e = blockIdx.x * 256 + threadIdx.x;
  if (e < EE) {
    int d = ei[EE + e];
    int pos = atomicAdd(&wp[d], 1);
    bucket[pos] = e;
  }
}

__global__ __launch_bounds__(256) void k_auxte(const float* __restrict__ tim,
                                               const float* __restrict__ tew_l,
                                               const float* __restrict__ teph_l,
                                               __bf16* __restrict__ aux) {
  int idx = blockIdx.x * 256 + threadIdx.x;   // e*16 + t
  int e = idx >> 4, t = idx & 15;
  float td = -tim[e];
  float wt = td * tew_l[t] + teph_l[t];
  float v = (t == 0) ? wt : __sinf(wt);
  aux[(size_t)e * 96 + 64 + t] = (__bf16)v;
}

// ---------------- h0 = [node_feat|memory] @ in_w^T + in_b  (LDS-staged A, 64-row) ----------------

__global__ __launch_bounds__(256) void k_h0(const float* __restrict__ nf,
                                            const float* __restrict__ mem,
                                            const __bf16* __restrict__ w,
                                            const float* __restrict__ bias,
                                            __bf16* __restrict__ hb) {
  __shared__ __bf16 As[64][264];
  const int t = threadIdx.x;
  const int lane = t & 63;
  const int wv = t >> 6;
  const int c = lane & 15, g = lane >> 4;
  const int row0 = blockIdx.x * 64;
  const int colbase = wv * 64;

  {
    const int col4 = t & 63;
    const int rb = t >> 6;
    const bool useMem = (col4 >= 32);
    const int coff = (useMem ? (col4 - 32) : col4) * 4;
    const float* basep = useMem ? mem : nf;
    #pragma unroll
    for (int i = 0; i < 16; ++i) {
      const int row = rb + i * 4;
      int grow = row0 + row; if (grow >= NN) grow = NN - 1;
      f32x4 v = *reinterpret_cast<const f32x4*>(basep + (size_t)grow * 128 + coff);
      bf16x4 bv;
      bv[0] = (__bf16)v[0]; bv[1] = (__bf16)v[1];
      bv[2] = (__bf16)v[2]; bv[3] = (__bf16)v[3];
      *reinterpret_cast<bf16x4*>(&As[row][col4 * 4]) = bv;
    }
  }
  __syncthreads();

  const __bf16* Bp[4];
  #pragma unroll
  for (int ct = 0; ct < 4; ++ct)
    Bp[ct] = w + (size_t)(colbase + ct * 16 + c) * 256;

  f32x4 acc[4][4];
  #pragma unroll
  for (int rt = 0; rt < 4; ++rt)
    for (int ct = 0; ct < 4; ++ct)
      for (int r = 0; r < 4; ++r) acc[rt][ct][r] = 0.0f;

  #pragma unroll
  for (int ks = 0; ks < 8; ++ks) {
    const int k = ks * 32 + g * 8;
    bf16x8 a[4], b[4];
    #pragma unroll
    for (int rt = 0; rt < 4; ++rt)
      a[rt] = *reinterpret_cast<const bf16x8*>(&As[rt * 16 + c][k]);
    #pragma unroll
    for (int ct = 0; ct < 4; ++ct) b[ct] = ld8(Bp[ct] + k);
    #pragma unroll
    for (int rt = 0; rt < 4; ++rt)
      #pragma unroll
      for (int ct = 0; ct < 4; ++ct)
        acc[rt][ct] = __builtin_amdgcn_mfma_f32_16x16x32_bf16(a[rt], b[ct], acc[rt][ct], 0, 0, 0);
  }
  __syncthreads();

  #pragma unroll
  for (int ct = 0; ct < 4; ++ct) {
    const float bv = bias[colbase + ct * 16 + c];
    #pragma unroll
    for (int rt = 0; rt < 4; ++rt)
      #pragma unroll
      for (int rr = 0; rr < 4; ++rr)
        As[rt * 16 + g * 4 + rr][colbase + ct * 16 + c] = (__bf16)(acc[rt][ct][rr] + bv);
  }
  #pragma unroll
  for (int i = 0; i < 8; ++i) {
    const int r = i * 8 + (lane >> 3);
    const int ck = lane & 7;
    bf16x8 v = *reinterpret_cast<const bf16x8*>(&As[r][colbase + ck * 8]);
    const int row = row0 + r;
    if (row < NN)
      *reinterpret_cast<bf16x8*>(hb + (size_t)row * 256 + colbase + ck * 8) = v;
  }
}

// ---------------- Qn/Kn GEMMs + fused per-head G (LDS-staged A) ----------------

__global__ __launch_bounds__(256, 2) void k_qkn(const __bf16* __restrict__ hb,
                                                const __bf16* __restrict__ wq_l,
                                                const __bf16* __restrict__ wk_l,
                                                const float* __restrict__ cq,
                                                const float* __restrict__ bk_l,
                                                const __bf16* __restrict__ twk_l,
                                                __bf16* __restrict__ Qn,
                                                __bf16* __restrict__ Kn,
                                                __bf16* __restrict__ G) {
  __shared__ __bf16 As[64][264];
  __shared__ __bf16 tile[4][64][84];
  const int lane = threadIdx.x & 63;
  const int wv = threadIdx.x >> 6;
  const int c = lane & 15, g = lane >> 4;
  const int row0 = blockIdx.x * 64;
  const int colbase = wv * 64;

  {
    #pragma unroll
    for (int i = 0; i < 8; ++i) {
      const int cc = threadIdx.x + i * 256;
      const int row = cc >> 5;
      const int col8 = cc & 31;
      int grow = row0 + row; if (grow >= NN) grow = NN - 1;
      *reinterpret_cast<bf16x8*>(&As[row][col8 * 8]) =
          ld8(hb + (size_t)grow * 256 + col8 * 8);
    }
  }
  __syncthreads();

  f32x4 acc[4][4];

  // ---- pass 1: Q ----
  #pragma unroll
  for (int rt = 0; rt < 4; ++rt)
    for (int ct = 0; ct < 4; ++ct)
      for (int r = 0; r < 4; ++r) acc[rt][ct][r] = 0.0f;
  {
    const __bf16* Bp[4];
    #pragma unroll
    for (int ct = 0; ct < 4; ++ct)
      Bp[ct] = wq_l + (size_t)(colbase + ct * 16 + c) * 272;
    #pragma unroll
    for (int ks = 0; ks < 8; ++ks) {
      const int k = ks * 32 + g * 8;
      bf16x8 a[4], b[4];
      #pragma unroll
      for (int rt = 0; rt < 4; ++rt)
        a[rt] = *reinterpret_cast<const bf16x8*>(&As[rt * 16 + c][k]);
      #pragma unroll
      for (int ct = 0; ct < 4; ++ct) b[ct] = ld8(Bp[ct] + k);
      #pragma unroll
      for (int rt = 0; rt < 4; ++rt)
        #pragma unroll
        for (int ct = 0; ct < 4; ++ct)
          acc[rt][ct] = __builtin_amdgcn_mfma_f32_16x16x32_bf16(a[rt], b[ct], acc[rt][ct], 0, 0, 0);
    }
  }
  #pragma unroll
  for (int ct = 0; ct < 4; ++ct) {
    const float cqv = cq[colbase + ct * 16 + c];
    #pragma unroll
    for (int rt = 0; rt < 4; ++rt)
      #pragma unroll
      for (int rr = 0; rr < 4; ++rr)
        tile[wv][rt * 16 + g * 4 + rr][ct * 16 + c] = (__bf16)(acc[rt][ct][rr] + cqv);
  }
  #pragma unroll
  for (int i = 0; i < 8; ++i) {
    const int r = i * 8 + (lane >> 3);
    const int ck = lane & 7;
    bf16x8 v = *reinterpret_cast<const bf16x8*>(&tile[wv][r][ck * 8]);
    const int row = row0 + r;
    if (row < NN)
      *reinterpret_cast<bf16x8*>(Qn + (size_t)row * 256 + colbase + ck * 8) = v;
  }

  // ---- fused G pass ----
  {
    f32x4 accg[4][5];
    #pragma unroll
    for (int rt = 0; rt < 4; ++rt)
      for (int ct = 0; ct < 5; ++ct)
        for (int r = 0; r < 4; ++r) accg[rt][ct][r] = 0.0f;
    const __bf16* Bp[5];
    #pragma unroll
    for (int ct = 0; ct < 5; ++ct)
      Bp[ct] = twk_l + (size_t)wv * 6144 + (size_t)(ct * 16 + c) * 64;
    #pragma unroll
    for (int ks = 0; ks < 2; ++ks) {
      const int k = ks * 32 + g * 8;
      bf16x8 a[4], b[5];
      #pragma unroll
      for (int rt = 0; rt < 4; ++rt)
        a[rt] = *reinterpret_cast<const bf16x8*>(&tile[wv][rt * 16 + c][k]);
      #pragma unroll
      for (int ct = 0; ct < 5; ++ct) b[ct] = ld8(Bp[ct] + k);
      #pragma unroll
      for (int rt = 0; rt < 4; ++rt)
        #pragma unroll
        for (int ct = 0; ct < 5; ++ct)
          accg[rt][ct] = __builtin_amdgcn_mfma_f32_16x16x32_bf16(a[rt], b[ct], accg[rt][ct], 0, 0, 0);
    }
    #pragma unroll
    for (int ct = 0; ct < 5; ++ct) {
      #pragma unroll
      for (int rt = 0; rt < 4; ++rt)
        #pragma unroll
        for (int rr = 0; rr < 4; ++rr)
          tile[wv][rt * 16 + g * 4 + rr][ct * 16 + c] = (__bf16)accg[rt][ct][rr];
    }
    #pragma unroll
    for (int i = 0; i < 10; ++i) {
      const int idx = i * 64 + lane;
      const int r = idx / 10;
      const int ck = idx % 10;
      bf16x8 v = *reinterpret_cast<const bf16x8*>(&tile[wv][r][ck * 8]);
      const int row = row0 + r;
      if (row < NN)
        *reinterpret_cast<bf16x8*>(G + (size_t)row * 320 + wv * 80 + ck * 8) = v;
    }
  }

  // ---- pass 2: K ----
  #pragma unroll
  for (int rt = 0; rt < 4; ++rt)
    for (int ct = 0; ct < 4; ++ct)
      for (int r = 0; r < 4; ++r) acc[rt][ct][r] = 0.0f;
  {
    const __bf16* Bp[4];
    #pragma unroll
    for (int ct = 0; ct < 4; ++ct)
      Bp[ct] = wk_l + (size_t)(colbase + ct * 16 + c) * 336;
    #pragma unroll
    for (int ks = 0; ks < 8; ++ks) {
      const int k = ks * 32 + g * 8;
      bf16x8 a[4], b[4];
      #pragma unroll
      for (int rt = 0; rt < 4; ++rt)
        a[rt] = *reinterpret_cast<const bf16x8*>(&As[rt * 16 + c][k]);
      #pragma unroll
      for (int ct = 0; ct < 4; ++ct) b[ct] = ld8(Bp[ct] + k);
      #pragma unroll
      for (int rt = 0; rt < 4; ++rt)
        #pragma unroll
        for (int ct = 0; ct < 4; ++ct)
          acc[rt][ct] = __builtin_amdgcn_mfma_f32_16x16x32_bf16(a[rt], b[ct], acc[rt][ct], 0, 0, 0);
    }
  }
  #pragma unroll
  for (int ct = 0; ct < 4; ++ct) {
    const float bkv = bk_l[colbase + ct * 16 + c];
    #pragma unroll
    for (int rt = 0; rt < 4; ++rt)
      #pragma unroll
      for (int rr = 0; rr < 4; ++rr)
        tile[wv][rt * 16 + g * 4 + rr][ct * 16 + c] = (__bf16)(acc[rt][ct][rr] + bkv);
  }
  #pragma unroll
  for (int i = 0; i < 8; ++i) {
    const int r = i * 8 + (lane >> 3);
    const int ck = lane & 7;
    bf16x8 v = *reinterpret_cast<const bf16x8*>(&tile[wv][r][ck * 8]);
    const int row = row0 + r;
    if (row < NN)
      *reinterpret_cast<bf16x8*>(Kn + (size_t)row * 256 + colbase + ck * 8) = v;
  }
}

// ---- fused score + CSR aggregate, chunk-4 + lane-parallel index prefetch ----
// (R9 configuration: 1 node/wave, 44 VGPR, occupancy ~41% -- proven optimum)

__global__ __launch_bounds__(256, 4) void k_sagg(const __bf16* __restrict__ hb,
                                                 const __bf16* __restrict__ aux,
                                                 const __bf16* __restrict__ G,
                                                 const __bf16* __restrict__ Qn,
                                                 const __bf16* __restrict__ Kn,
                                                 const int* __restrict__ ei,
                                                 const int* __restrict__ rowptr,
                                                 const int* __restrict__ bucket,
                                                 __bf16* __restrict__ maggH,
                                                 __bf16* __restrict__ maggX,
                                                 float* __restrict__ sfac) {
  const int lane = threadIdx.x & 63;
  const int wv = threadIdx.x >> 6;
  const int node = blockIdx.x * 4 + wv;
  const int beg = rowptr[node], end = rowptr[node + 1];
  const int deg = end - beg;
  const int c = lane & 15;
  const int grp = lane >> 4;

  float aH[4] = {0, 0, 0, 0};
  float aXv[4] = {0, 0, 0, 0};
  float aXs = 0.0f;
  float nrm = 0.0f;

  if (deg > 0) {
    const int iq = ei[EE + node];
    const __bf16* Qr = Qn + (size_t)iq * 256;
    const __bf16* Gr = G + (size_t)iq * 320;

    bf16x4 qv = ld4(Qr + lane * 4);
    bf16x4 gv = ld4(Gr + grp * 80 + c * 4);
    const float gs = (float)Gr[grp * 80 + 64 + c];

    // lane-parallel index prefetch (covers first 64 edges; deg>64 near-impossible)
    int eL = 0, sL = 0;
    const int degc = (deg < 64) ? deg : 64;
    if (lane < degc) eL = bucket[beg + lane];
    if (lane < degc) sL = ei[eL];

    for (int base = 0; base < deg; base += 4) {
      const int rem = deg - base;
      const int iA = base;
      const int iB = base + ((1 < rem) ? 1 : 0);
      const int iC = base + ((2 < rem) ? 2 : 0);
      const int iD = base + ((3 < rem) ? 3 : 0);
      int eA = __shfl(eL, (iA < 64) ? iA : 0, 64);
      int sA = __shfl(sL, (iA < 64) ? iA : 0, 64);
      int eB = __shfl(eL, (iB < 64) ? iB : 0, 64);
      int sB = __shfl(sL, (iB < 64) ? iB : 0, 64);
      int eC = __shfl(eL, (iC < 64) ? iC : 0, 64);
      int sC = __shfl(sL, (iC < 64) ? iC : 0, 64);
      int eD = __shfl(eL, (iD < 64) ? iD : 0, 64);
      int sD = __shfl(sL, (iD < 64) ? iD : 0, 64);
      if (iD >= 64) {                      // wave-uniform; rare tail
        if (iA >= 64) { eA = bucket[beg + iA]; sA = ei[eA]; }
        if (iB >= 64) { eB = bucket[beg + iB]; sB = ei[eB]; }
        if (iC >= 64) { eC = bucket[beg + iC]; sC = ei[eC]; }
        eD = bucket[beg + iD]; sD = ei[eD];
      }

      bf16x4 kvA = ld4(Kn + (size_t)sA * 256 + lane * 4);
      bf16x4 kvB = ld4(Kn + (size_t)sB * 256 + lane * 4);
      bf16x4 kvC = ld4(Kn + (size_t)sC * 256 + lane * 4);
      bf16x4 kvD = ld4(Kn + (size_t)sD * 256 + lane * 4);
      bf16x4 hvA = ld4(hb + (size_t)sA * 256 + lane * 4);
      bf16x4 hvB = ld4(hb + (size_t)sB * 256 + lane * 4);
      bf16x4 hvC = ld4(hb + (size_t)sC * 256 + lane * 4);
      bf16x4 hvD = ld4(hb + (size_t)sD * 256 + lane * 4);
      bf16x4 avA = ld4(aux + (size_t)eA * 96 + c * 4);
      bf16x4 avB = ld4(aux + (size_t)eB * 96 + c * 4);
      bf16x4 avC = ld4(aux + (size_t)eC * 96 + c * 4);
      bf16x4 avD = ld4(aux + (size_t)eD * 96 + c * 4);
      const float asA = (float)aux[(size_t)eA * 96 + 64 + c];
      const float asB = (float)aux[(size_t)eB * 96 + 64 + c];
      const float asC = (float)aux[(size_t)eC * 96 + 64 + c];
      const float asD = (float)aux[(size_t)eD * 96 + 64 + c];

      float pA = gs * asA, pB = gs * asB, pC = gs * asC, pD = gs * asD;
      #pragma unroll
      for (int j = 0; j < 4; ++j) {
        const float qj = (float)qv[j], gj = (float)gv[j];
        pA += qj * (float)kvA[j] + gj * (float)avA[j];
        pB += qj * (float)kvB[j] + gj * (float)avB[j];
        pC += qj * (float)kvC[j] + gj * (float)avC[j];
        pD += qj * (float)kvD[j] + gj * (float)avD[j];
      }
      #pragma unroll
      for (int m = 1; m <= 8; m <<= 1) {
        pA += __shfl_xor(pA, m, 64);
        pB += __shfl_xor(pB, m, 64);
        pC += __shfl_xor(pC, m, 64);
        pD += __shfl_xor(pD, m, 64);
      }
      float exA = __expf(fminf(5.0f, fmaxf(-5.0f, pA * 0.125f)));
      float exB = __expf(fminf(5.0f, fmaxf(-5.0f, pB * 0.125f)));
      float exC = __expf(fminf(5.0f, fmaxf(-5.0f, pC * 0.125f)));
      float exD = __expf(fminf(5.0f, fmaxf(-5.0f, pD * 0.125f)));
      exA += __shfl_xor(exA, 16, 64);
      exB += __shfl_xor(exB, 16, 64);
      exC += __shfl_xor(exC, 16, 64);
      exD += __shfl_xor(exD, 16, 64);
      exA += __shfl_xor(exA, 32, 64);
      exB += __shfl_xor(exB, 32, 64);
      exC += __shfl_xor(exC, 32, 64);
      exD += __shfl_xor(exD, 32, 64);
      const float aA = exA * 0.25f;
      const float aB = (1 < rem) ? exB * 0.25f : 0.0f;
      const float aC = (2 < rem) ? exC * 0.25f : 0.0f;
      const float aD = (3 < rem) ? exD * 0.25f : 0.0f;

      nrm += aA + aB + aC + aD;
      #pragma unroll
      for (int j = 0; j < 4; ++j)
        aH[j] += aA * (float)hvA[j] + aB * (float)hvB[j] +
                 aC * (float)hvC[j] + aD * (float)hvD[j];
      if (grp == 0) {
        #pragma unroll
        for (int j = 0; j < 4; ++j)
          aXv[j] += aA * (float)avA[j] + aB * (float)avB[j] +
                    aC * (float)avC[j] + aD * (float)avD[j];
      } else if (grp == 1) {
        aXs += aA * asA + aB * asB + aC * asC + aD * asD;
      }
    }
  }

  const float inv = 1.0f / (nrm + 1e-8f);
  bf16x4 oh;
  #pragma unroll
  for (int j = 0; j < 4; ++j) oh[j] = (__bf16)(aH[j] * inv);
  *reinterpret_cast<bf16x4*>(maggH + (size_t)node * 256 + lane * 4) = oh;
  if (grp == 0) {
    bf16x4 ox;
    #pragma unroll
    for (int j = 0; j < 4; ++j) ox[j] = (__bf16)(aXv[j] * inv);
    *reinterpret_cast<bf16x4*>(maggX + (size_t)node * 96 + c * 4) = ox;
  } else if (grp == 1) {
    maggX[(size_t)node * 96 + 64 + c] = (__bf16)(aXs * inv);
  } else if (grp == 2) {
    maggX[(size_t)node * 96 + 80 + c] = (__bf16)0.0f;
  }
  if (lane == 0) sfac[node] = nrm * inv;
}

// ---- small-workspace fallback: score-only (af) + separate aggregate ----

__global__ __launch_bounds__(256, 4) void k_score3(const __bf16* __restrict__ aux,
                                                   const __bf16* __restrict__ G,
                                                   const __bf16* __restrict__ Qn,
                                                   const __bf16* __restrict__ Kn,
                                                   const int* __restrict__ ei,
                                                   const int* __restrict__ rowptr,
                                                   const int* __restrict__ bucket,
                                                   float* __restrict__ af) {
  const int lane = threadIdx.x & 63;
  const int wv = threadIdx.x >> 6;
  const int node = blockIdx.x * 4 + wv;
  const int beg = rowptr[node], end = rowptr[node + 1];
  const int c = lane & 15;
  const int grp = lane >> 4;

  if (beg < end) {
    const int iq = ei[EE + node];
    const __bf16* Qr = Qn + (size_t)iq * 256;
    const __bf16* Gr = G + (size_t)iq * 320;

    bf16x4 qv = ld4(Qr + lane * 4);
    bf16x4 gv = ld4(Gr + grp * 80 + c * 4);
    const float gs = (float)Gr[grp * 80 + 64 + c];

    int e = bucket[beg];
    int s = ei[e];
    for (int i = beg; i < end; ++i) {
      const int en = (i + 1 < end) ? bucket[i + 1] : e;
      const int sn = ei[en];
      bf16x4 kv = ld4(Kn + (size_t)s * 256 + lane * 4);
      bf16x4 av = ld4(aux + (size_t)e * 96 + c * 4);
      float as = (float)aux[(size_t)e * 96 + 64 + c];

      float p = gs * as;
      #pragma unroll
      for (int j = 0; j < 4; ++j) {
        p += (float)qv[j] * (float)kv[j];
        p += (float)gv[j] * (float)av[j];
      }
      p += __shfl_xor(p, 1, 64);
      p += __shfl_xor(p, 2, 64);
      p += __shfl_xor(p, 4, 64);
      p += __shfl_xor(p, 8, 64);
      float sc = fminf(5.0f, fmaxf(-5.0f, p * 0.125f));
      float ex = __expf(sc);
      ex += __shfl_xor(ex, 16, 64);
      ex += __shfl_xor(ex, 32, 64);
      if (lane == 0) af[e] = ex * 0.25f;
      e = en; s = sn;
    }
  }
}

__global__ __launch_bounds__(256, 4) void k_magg(const __bf16* __restrict__ hb,
                                                 const __bf16* __restrict__ aux,
                                                 const int* __restrict__ ei,
                                                 const int* __restrict__ rowptr,
                                                 const int* __restrict__ bucket,
                                                 const float* __restrict__ af,
                                                 __bf16* __restrict__ maggH,
                                                 __bf16* __restrict__ maggX,
                                                 float* __restrict__ sfac) {
  const int lane = threadIdx.x & 63;
  const int wv = threadIdx.x >> 6;
  const int node = blockIdx.x * 4 + wv;
  const int beg = rowptr[node], end = rowptr[node + 1];

  float aH[4] = {0, 0, 0, 0};
  float aX[2] = {0, 0};
  float nrm = 0.0f;
  if (beg < end) {
    int e = bucket[beg];
    float a = af[e];
    int s = ei[e];
    for (int i = beg; i < end; ++i) {
      const int en = (i + 1 < end) ? bucket[i + 1] : e;
      const float an = af[en];
      const int sn = ei[en];
      bf16x4 hv = ld4(hb + (size_t)s * 256 + lane * 4);
      #pragma unroll
      for (int j = 0; j < 4; ++j) aH[j] += a * (float)hv[j];
      if (lane < 48) {
        bf16x2 xv = *reinterpret_cast<const bf16x2*>(aux + (size_t)e * 96 + lane * 2);
        aX[0] += a * (float)xv[0];
        aX[1] += a * (float)xv[1];
      }
      nrm += a;
      e = en; a = an; s = sn;
    }
  }
  const float inv = 1.0f / (nrm + 1e-8f);
  bf16x4 oh;
  #pragma unroll
  for (int j = 0; j < 4; ++j) oh[j] = (__bf16)(aH[j] * inv);
  *reinterpret_cast<bf16x4*>(maggH + (size_t)node * 256 + lane * 4) = oh;
  if (lane < 48) {
    bf16x2 ox;
    ox[0] = (__bf16)(aX[0] * inv);
    ox[1] = (__bf16)(aX[1] * inv);
    *reinterpret_cast<bf16x2*>(maggX + (size_t)node * 96 + lane * 2) = ox;
  }
  if (lane == 0) sfac[node] = nrm * inv;
}

// ---- fused V-GEMM + double layer-norm (+ fused out-GEMM on last layer) ----
// single full-width LDS buffer As[64][360]: cols 0..255 maggH (then hb, then
// h_new), cols 256..351 maggX. All MFMA A-operands come from LDS.

__global__ __launch_bounds__(256, 3) void k_vnorm(const __bf16* __restrict__ maggH,
                                                  const __bf16* __restrict__ maggX,
                                                  const float* __restrict__ sfac,
                                                  const __bf16* __restrict__ wv_l,
                                                  const float* __restrict__ bv_l,
                                                  __bf16* __restrict__ hb,
                                                  const float* __restrict__ aw,
                                                  const float* __restrict__ ab,
                                                  const float* __restrict__ lw,
                                                  const float* __restrict__ lb,
                                                  const __bf16* __restrict__ cow,
                                                  const float* __restrict__ obias,
                                                  float* __restrict__ outp,
                                                  int last) {
  __shared__ __bf16 As[64][360];
  __shared__ float redA[64][4];
  __shared__ float redB[64][4];
  const int t = threadIdx.x;
  const int lane = t & 63;
  const int wv = t >> 6;
  const int c = lane & 15, g = lane >> 4;
  const int row0 = blockIdx.x * 64;
  const int colbase = wv * 64;

  // ---- stage maggH (cols 0..255) + maggX (cols 256..351), coalesced ----
  #pragma unroll
  for (int i = 0; i < 8; ++i) {
    const int cc = t + i * 256;
    const int row = cc >> 5;
    const int col8 = cc & 31;
    int grow = row0 + row; if (grow >= NN) grow = NN - 1;
    *reinterpret_cast<bf16x8*>(&As[row][col8 * 8]) =
        ld8(maggH + (size_t)grow * 256 + col8 * 8);
  }
  #pragma unroll
  for (int i = 0; i < 3; ++i) {
    const int cc = t + i * 256;     // < 768 = 64 rows * 12 chunks
    const int row = cc / 12;
    const int col8 = cc % 12;
    int grow = row0 + row; if (grow >= NN) grow = NN - 1;
    *reinterpret_cast<bf16x8*>(&As[row][256 + col8 * 8]) =
        ld8(maggX + (size_t)grow * 96 + col8 * 8);
  }
  __syncthreads();

  const __bf16* Bp[4];
  #pragma unroll
  for (int ct = 0; ct < 4; ++ct)
    Bp[ct] = wv_l + (size_t)(colbase + ct * 16 + c) * 336;

  f32x4 acc[4][4];
  #pragma unroll
  for (int rt = 0; rt < 4; ++rt)
    for (int ct = 0; ct < 4; ++ct)
      for (int r = 0; r < 4; ++r) acc[rt][ct][r] = 0.0f;

  #pragma unroll
  for (int ks = 0; ks < 8; ++ks) {
    const int k = ks * 32 + g * 8;
    bf16x8 a[4], b[4];
    #pragma unroll
    for (int rt = 0; rt < 4; ++rt)
      a[rt] = *reinterpret_cast<const bf16x8*>(&As[rt * 16 + c][k]);
    #pragma unroll
    for (int ct = 0; ct < 4; ++ct) b[ct] = ld8(Bp[ct] + k);
    #pragma unroll
    for (int rt = 0; rt < 4; ++rt)
      #pragma unroll
      for (int ct = 0; ct < 4; ++ct)
        acc[rt][ct] = __builtin_amdgcn_mfma_f32_16x16x32_bf16(a[rt], b[ct], acc[rt][ct], 0, 0, 0);
  }
  const bf16x8 bz = zero8();
  #pragma unroll
  for (int ks = 0; ks < 3; ++ks) {
    const int kk = ks * 32 + g * 8;
    bf16x8 a[4], b[4];
    #pragma unroll
    for (int rt = 0; rt < 4; ++rt)
      a[rt] = *reinterpret_cast<const bf16x8*>(&As[rt * 16 + c][256 + kk]);
    #pragma unroll
    for (int ct = 0; ct < 4; ++ct)
      b[ct] = (kk < 80) ? ld8(Bp[ct] + 256 + kk) : bz;
    #pragma unroll
    for (int rt = 0; rt < 4; ++rt)
      #pragma unroll
      for (int ct = 0; ct < 4; ++ct)
        acc[rt][ct] = __builtin_amdgcn_mfma_f32_16x16x32_bf16(a[rt], b[ct], acc[rt][ct], 0, 0, 0);
  }

  // ---- re-stage As cols 0..255 with hb residual ----
  __syncthreads();
  #pragma unroll
  for (int i = 0; i < 8; ++i) {
    const int cc = t + i * 256;
    const int row = cc >> 5;
    const int col8 = cc & 31;
    int grow = row0 + row; if (grow >= NN) grow = NN - 1;
    *reinterpret_cast<bf16x8*>(&As[row][col8 * 8]) =
        ld8(hb + (size_t)grow * 256 + col8 * 8);
  }
  __syncthreads();

  float sf[4][4];
  #pragma unroll
  for (int rt = 0; rt < 4; ++rt)
    #pragma unroll
    for (int rr = 0; rr < 4; ++rr) {
      int row = row0 + rt * 16 + g * 4 + rr; if (row >= NN) row = NN - 1;
      sf[rt][rr] = sfac[row];
    }
  float bvv[4], awv[4], abv[4], lwv[4], lbv[4];
  #pragma unroll
  for (int ct = 0; ct < 4; ++ct) {
    const int col = colbase + ct * 16 + c;
    bvv[ct] = bv_l[col];
    awv[ct] = aw[col]; abv[ct] = ab[col];
    lwv[ct] = lw[col]; lbv[ct] = lb[col];
  }
  #pragma unroll
  for (int rt = 0; rt < 4; ++rt)
    #pragma unroll
    for (int ct = 0; ct < 4; ++ct)
      #pragma unroll
      for (int rr = 0; rr < 4; ++rr)
        acc[rt][ct][rr] += sf[rt][rr] * bvv[ct];

  // ---- LN1 mean ----
  float s1[4][4];
  #pragma unroll
  for (int rt = 0; rt < 4; ++rt)
    #pragma unroll
    for (int rr = 0; rr < 4; ++rr) {
      float s = 0.0f;
      #pragma unroll
      for (int ct = 0; ct < 4; ++ct) s += acc[rt][ct][rr];
      #pragma unroll
      for (int m = 1; m < 16; m <<= 1) s += __shfl_xor(s, m, 64);
      s1[rt][rr] = s;
    }
  if (c == 0)
    #pragma unroll
    for (int rt = 0; rt < 4; ++rt)
      #pragma unroll
      for (int rr = 0; rr < 4; ++rr)
        redA[rt * 16 + g * 4 + rr][wv] = s1[rt][rr];
  __syncthreads();
  float mean1[4][4];
  #pragma unroll
  for (int rt = 0; rt < 4; ++rt)
    #pragma unroll
    for (int rr = 0; rr < 4; ++rr) {
      const int r = rt * 16 + g * 4 + rr;
      mean1[rt][rr] = (redA[r][0] + redA[r][1] + redA[r][2] + redA[r][3]) * (1.0f / 256.0f);
    }
  // ---- LN1 var ----
  #pragma unroll
  for (int rt = 0; rt < 4; ++rt)
    #pragma unroll
    for (int rr = 0; rr < 4; ++rr) {
      float q = 0.0f;
      #pragma unroll
      for (int ct = 0; ct < 4; ++ct) {
        float d = acc[rt][ct][rr] - mean1[rt][rr];
        q += d * d;
      }
      #pragma unroll
      for (int m = 1; m < 16; m <<= 1) q += __shfl_xor(q, m, 64);
      s1[rt][rr] = q;
    }
  if (c == 0)
    #pragma unroll
    for (int rt = 0; rt < 4; ++rt)
      #pragma unroll
      for (int rr = 0; rr < 4; ++rr)
        redB[rt * 16 + g * 4 + rr][wv] = s1[rt][rr];
  __syncthreads();
  float rstd1[4][4];
  #pragma unroll
  for (int rt = 0; rt < 4; ++rt)
    #pragma unroll
    for (int rr = 0; rr < 4; ++rr) {
      const int r = rt * 16 + g * 4 + rr;
      float v = (redB[r][0] + redB[r][1] + redB[r][2] + redB[r][3]) * (1.0f / 256.0f);
      rstd1[rt][rr] = rsqrtf(v + 1e-5f);
    }

  // ---- y = hb + LN1(x)*aw + ab ; LN2 mean ----
  #pragma unroll
  for (int rt = 0; rt < 4; ++rt)
    #pragma unroll
    for (int rr = 0; rr < 4; ++rr) {
      const int r = rt * 16 + g * 4 + rr;
      float s = 0.0f;
      #pragma unroll
      for (int ct = 0; ct < 4; ++ct) {
        float hbv = (float)As[r][colbase + ct * 16 + c];
        float y = hbv + (acc[rt][ct][rr] - mean1[rt][rr]) * rstd1[rt][rr] * awv[ct] + abv[ct];
        acc[rt][ct][rr] = y;
        s += y;
      }
      #pragma unroll
      for (int m = 1; m < 16; m <<= 1) s += __shfl_xor(s, m, 64);
      s1[rt][rr] = s;
    }
  if (c == 0)
    #pragma unroll
    for (int rt = 0; rt < 4; ++rt)
      #pragma unroll
      for (int rr = 0; rr < 4; ++rr)
        redA[rt * 16 + g * 4 + rr][wv] = s1[rt][rr];
  __syncthreads();
  float mean2[4][4];
  #pragma unroll
  for (int rt = 0; rt < 4; ++rt)
    #pragma unroll
    for (int rr = 0; rr < 4; ++rr) {
      const int r = rt * 16 + g * 4 + rr;
      mean2[rt][rr] = (redA[r][0] + redA[r][1] + redA[r][2] + redA[r][3]) * (1.0f / 256.0f);
    }
  // ---- LN2 var ----
  #pragma unroll
  for (int rt = 0; rt < 4; ++rt)
    #pragma unroll
    for (int rr = 0; rr < 4; ++rr) {
      float q = 0.0f;
      #pragma unroll
      for (int ct = 0; ct < 4; ++ct) {
        float d = acc[rt][ct][rr] - mean2[rt][rr];
        q += d * d;
      }
      #pragma unroll
      for (int m = 1; m < 16; m <<= 1) q += __shfl_xor(q, m, 64);
      s1[rt][rr] = q;
    }
  if (c == 0)
    #pragma unroll
    for (int rt = 0; rt < 4; ++rt)
      #pragma unroll
      for (int rr = 0; rr < 4; ++rr)
        redB[rt * 16 + g * 4 + rr][wv] = s1[rt][rr];
  __syncthreads();
  #pragma unroll
  for (int rt = 0; rt < 4; ++rt)
    #pragma unroll
    for (int rr = 0; rr < 4; ++rr) {
      const int r = rt * 16 + g * 4 + rr;
      float v = (redB[r][0] + redB[r][1] + redB[r][2] + redB[r][3]) * (1.0f / 256.0f);
      const float rstd2 = rsqrtf(v + 1e-5f);
      #pragma unroll
      for (int ct = 0; ct < 4; ++ct)
        As[r][colbase + ct * 16 + c] =
            (__bf16)((acc[rt][ct][rr] - mean2[rt][rr]) * rstd2 * lwv[ct] + lbv[ct]);
    }
  __syncthreads();

  if (!last) {
    // coalesced writeback of new hb
    #pragma unroll
    for (int i = 0; i < 8; ++i) {
      const int cc = t + i * 256;
      const int row = cc >> 5;
      const int col8 = cc & 31;
      const int grow = row0 + row;
      if (grow < NN)
        *reinterpret_cast<bf16x8*>(hb + (size_t)grow * 256 + col8 * 8) =
            *reinterpret_cast<const bf16x8*>(&As[row][col8 * 8]);
    }
  } else {
    // fused out = gelu(h_new @ out_w^T + out_b); h_new lives in As
    const __bf16* Bop = cow + (size_t)(wv * 16 + c) * 256;
    f32x4 acc2[4];
    #pragma unroll
    for (int rt = 0; rt < 4; ++rt)
      for (int rr = 0; rr < 4; ++rr) acc2[rt][rr] = 0.0f;
    #pragma unroll
    for (int ks = 0; ks < 8; ++ks) {
      const int k = ks * 32 + g * 8;
      bf16x8 bfrag = ld8(Bop + k);
      #pragma unroll
      for (int rt = 0; rt < 4; ++rt) {
        bf16x8 afrag = *reinterpret_cast<const bf16x8*>(&As[rt * 16 + c][k]);
        acc2[rt] = __builtin_amdgcn_mfma_f32_16x16x32_bf16(afrag, bfrag, acc2[rt], 0, 0, 0);
      }
    }
    const int col = wv * 16 + c;
    const float bo = obias[col];
    #pragma unroll
    for (int rt = 0; rt < 4; ++rt)
      #pragma unroll
      for (int rr = 0; rr < 4; ++rr) {
        const int row = row0 + rt * 16 + g * 4 + rr;
        if (row < NN) {
          float x = acc2[rt][rr] + bo;
          outp[(size_t)row * 64 + col] = 0.5f * x * (1.0f + erff(x * 0.70710678118654752f));
        }
      }
  }
}

// ---------------- launcher ----------------

extern "C" void kernel_launch(void* const* d_in, const int* in_sizes, int n_in,
                              void* d_out, int out_size, void* d_ws, size_t ws_size,
                              hipStream_t stream) {
  (void)in_sizes; (void)n_in; (void)out_size;
  const float* nf   = (const float*)d_in[0];
  const float* mem  = (const float*)d_in[1];
  const int*   ei   = (const int*)d_in[2];
  const float* ef   = (const float*)d_in[3];
  const float* tim  = (const float*)d_in[4];
  const float* inw  = (const float*)d_in[5];
  const float* inb  = (const float*)d_in[6];
  const float* tew  = (const float*)d_in[7];
  const float* teph = (const float*)d_in[8];
  const float* wq   = (const float*)d_in[9];
  const float* wqb  = (const float*)d_in[10];
  const float* wk   = (const float*)d_in[11];
  const float* wkb  = (const float*)d_in[12];
  const float* wvw  = (const float*)d_in[13];
  const float* wvb  = (const float*)d_in[14];
  const float* alw  = (const float*)d_in[15];
  const float* alb  = (const float*)d_in[16];
  const float* lnw  = (const float*)d_in[17];
  const float* lnb  = (const float*)d_in[18];
  const float* ow   = (const float*)d_in[19];
  const float* ob   = (const float*)d_in[20];
  float* out = (float*)d_out;

  char* ws = (char*)d_ws;
  // Fused k_sagg reads G while writing maggH/maggX -> they must be disjoint.
  // That needs ~186.7 MB; fall back to split score+aggregate (aliased layout) otherwise.
  const bool big = ws_size >= 186700000ULL;

  __bf16* hb    = (__bf16*)(ws + 0);            // N*256 bf16  = 25,600,000
  __bf16* aux   = (__bf16*)(ws + 25600000);     // E*96 bf16   = 38,400,000
  __bf16* Qn    = (__bf16*)(ws + 64000000);     // N*256 bf16  = 25,600,000
  __bf16* Kn    = (__bf16*)(ws + 89600000);     // N*256 bf16  = 25,600,000
  __bf16* G     = (__bf16*)(ws + 115200000);    // N*320 bf16  = 32,000,000 -> ends 147,200,000
  // big: magg after G (disjoint). small: magg aliases G (legal: split kernels, disjoint in time)
  __bf16* maggH = (__bf16*)(ws + (big ? 147200000 : 115200000));   // N*256 bf16
  __bf16* maggX = (__bf16*)(ws + (big ? 172800000 : 140800000));   // N*96 bf16
  const size_t o_tail = big ? 182400000 : 150400000;
  float*  sfac  = (float*) (ws + o_tail);             // N f32
  float*  af    = (float*) (ws + o_tail + 200000);    // E f32 (small path only)
  int*    rowptr= (int*)   (ws + o_tail + 1800000);   // (N+1) int
  int*    wp    = (int*)   (ws + o_tail + 2000192);   // N int
  int*    bucket= (int*)   (ws + o_tail + 2200192);   // E int
  float*  cq    = (float*) (ws + o_tail + 3000192);   // 2*256 f32
  int*    bsum  = (int*)   (ws + o_tail + 3002240);   // 196 int
  __bf16* cinw  = (__bf16*)(ws + o_tail + 3003264);   // 131,072
  __bf16* cwq   = (__bf16*)(ws + o_tail + 3134336);   // 278,528
  __bf16* cwk   = (__bf16*)(ws + o_tail + 3412864);   // 344,064
  __bf16* cwv   = (__bf16*)(ws + o_tail + 3756928);   // 344,064
  __bf16* cow   = (__bf16*)(ws + o_tail + 4100992);   // 32,768
  __bf16* twk   = (__bf16*)(ws + o_tail + 4133760);   // 98,304 -> end o_tail+4,232,064

  const int NB = (NN + 255) / 256;   // 196
  hipMemsetAsync(wp, 0, NN * 4, stream);
  k_prep<<<28184, 256, 0, stream>>>(inw, wq, wk, wvw, ow, ef, tim, tew, teph, wqb, ei,
                                    cinw, cwq, cwk, cwv, cow, twk, aux, cq, wp);
  k_blksum<<<NB, 256, 0, stream>>>(wp, bsum);
  k_scanb<<<1, 256, 0, stream>>>(bsum, NB);
  k_scanc<<<NB, 256, 0, stream>>>(wp, bsum, rowptr);
  k_fill<<<(EE + 255) / 256, 256, 0, stream>>>(ei, wp, bucket);

  k_h0<<<(NN + 63) / 64, 256, 0, stream>>>(nf, mem, cinw, inb, hb);

  for (int l = 0; l < 2; ++l) {
    const __bf16* wq_l = cwq + (size_t)l * 256 * 272;
    const __bf16* wk_l = cwk + (size_t)l * 256 * 336;
    const __bf16* wv_l = cwv + (size_t)l * 256 * 336;
    if (l > 0)
      k_auxte<<<EE * 16 / 256, 256, 0, stream>>>(tim, tew + l * 16, teph + l * 16, aux);
    k_qkn<<<(NN + 63) / 64, 256, 0, stream>>>(hb, wq_l, wk_l, cq + l * 256, wkb + l * 256,
                                              twk + (size_t)l * 24576, Qn, Kn, G);
    if (big) {
      k_sagg<<<NN / 4, 256, 0, stream>>>(hb, aux, G, Qn, Kn, ei, rowptr, bucket,
                                         maggH, maggX, sfac);
    } else {
      k_score3<<<NN / 4, 256, 0, stream>>>(aux, G, Qn, Kn, ei, rowptr, bucket, af);
      k_magg<<<NN / 4, 256, 0, stream>>>(hb, aux, ei, rowptr, bucket, af, maggH, maggX, sfac);
    }
    k_vnorm<<<(NN + 63) / 64, 256, 0, stream>>>(maggH, maggX, sfac, wv_l, wvb + l * 256, hb,
                                                alw + l * 256, alb + l * 256,
                                                lnw + l * 256, lnb + l * 256,
                                                cow, ob, out, (l == 1) ? 1 : 0);
  }
}